// Round 1
// baseline (921.994 us; speedup 1.0000x reference)
//
#include <hip/hip_runtime.h>
#include <math.h>

#define IMG 56
#define HW 3136          // 56*56
#define NCH 256
#define NB 32
#define SAMPLE (NCH*HW)  // 802816
#define TOT (NB*SAMPLE)  // 25690112

// ---------- helpers ----------

__device__ __forceinline__ float qz(float x, float mn, float scale) {
    float t = (x - mn) / scale;
    t = fminf(fmaxf(t, 0.f), 255.f);
    return rintf(t) * scale + mn;   // rintf = round-half-even, matches jnp.round
}

// order-preserving float<->uint encode for atomicMin/Max on floats
__device__ __forceinline__ unsigned enc(float f) {
    unsigned u = __float_as_uint(f);
    return (u & 0x80000000u) ? ~u : (u ^ 0x80000000u);
}
__device__ __forceinline__ float dec(unsigned u) {
    unsigned v = (u & 0x80000000u) ? (u ^ 0x80000000u) : ~u;
    return __uint_as_float(v);
}

// block-level min/max reduce (result valid on thread 0). blockDim must be mult of 64.
__device__ __forceinline__ void blk_red_minmax(float& mn, float& mx) {
    __shared__ float smn[4], smx[4];
    __syncthreads();   // protect shared reuse across successive calls
    #pragma unroll
    for (int o = 32; o > 0; o >>= 1) {
        mn = fminf(mn, __shfl_down(mn, o));
        mx = fmaxf(mx, __shfl_down(mx, o));
    }
    int lane = threadIdx.x & 63, w = threadIdx.x >> 6;
    if (lane == 0) { smn[w] = mn; smx[w] = mx; }
    __syncthreads();
    if (threadIdx.x == 0) {
        int nw = (int)blockDim.x >> 6;
        for (int i = 1; i < nw; i++) { mn = fminf(mn, smn[i]); mx = fmaxf(mx, smx[i]); }
    }
}

__device__ __forceinline__ float blk_red_sum(float v) {
    __shared__ float ss[4];
    __syncthreads();
    #pragma unroll
    for (int o = 32; o > 0; o >>= 1) v += __shfl_down(v, o);
    int lane = threadIdx.x & 63, w = threadIdx.x >> 6;
    if (lane == 0) ss[w] = v;
    __syncthreads();
    if (threadIdx.x == 0) {
        int nw = (int)blockDim.x >> 6;
        for (int i = 1; i < nw; i++) v += ss[i];
    }
    return v;
}

// ---------- kernels ----------

// stats slot layout (uint view): [0..31] min_x  [32..63] max_x
// [64..95] min_h1 [96..127] max_h1 [128..159] min_h2 [160..191] max_h2
// [192..223] min_o2 [224..255] max_o2
__global__ void k_init(unsigned* statsu) {
    int t = threadIdx.x;
    statsu[t] = ((t >> 5) & 1) ? 0u : 0xFFFFFFFFu;
}

// per-sample min/max of x. grid (16 chunks, 32 samples)
__global__ __launch_bounds__(256) void k_minmax_x(const float4* __restrict__ x4, unsigned* statsu) {
    int b = blockIdx.y, blk = blockIdx.x;
    const float4* p = x4 + (size_t)b * 200704 + (size_t)blk * 12544;
    float mn = INFINITY, mx = -INFINITY;
    for (int k = threadIdx.x; k < 12544; k += 256) {
        float4 v = p[k];
        mn = fminf(mn, fminf(fminf(v.x, v.y), fminf(v.z, v.w)));
        mx = fmaxf(mx, fmaxf(fmaxf(v.x, v.y), fmaxf(v.z, v.w)));
    }
    blk_red_minmax(mn, mx);
    if (threadIdx.x == 0) {
        atomicMin(&statsu[b], enc(mn));
        atomicMax(&statsu[32 + b], enc(mx));
    }
}

// sc layout (float): 0 mn_x 1 s_x | 2 mn_w1 3 s_w1 | 4 mn_b1 5 s_b1 | 6 mn_h1 7 s_h1
//                    8 mn_h2 9 s_h2 | 10 mn_w2 11 s_w2 | 12 mn_o2 13 s_o2
__global__ void k_fin1(const float* __restrict__ dww, const float* __restrict__ dwb,
                       const unsigned* __restrict__ statsu, float* sc) {
    int tid = threadIdx.x;
    float mn = INFINITY, mx = -INFINITY;
    for (int i = tid; i < 2304; i += 256) { float v = dww[i]; mn = fminf(mn, v); mx = fmaxf(mx, v); }
    blk_red_minmax(mn, mx);
    float w1min = mn, w1max = mx;                 // valid on tid 0
    float v = dwb[tid]; mn = v; mx = v;
    blk_red_minmax(mn, mx);
    if (tid == 0) {
        float sm = 0.f, sx = 0.f;
        for (int i = 0; i < 32; i++) { sm += dec(statsu[i]); sx += dec(statsu[32 + i]); }
        float m = sm / 32.f, X = sx / 32.f;
        sc[0] = m;      sc[1] = fmaxf((X - m) / 255.f, 1e-8f);
        sc[2] = w1min;  sc[3] = fmaxf((w1max - w1min) / 255.f, 1e-8f);
        sc[4] = mn;     sc[5] = fmaxf((mx - mn) / 255.f, 1e-8f);
    }
}

// depthwise 3x3 pad=1 on quantized input/weight/bias, fused per-sample min/max of h1
__global__ __launch_bounds__(256) void k_dwconv(const float* __restrict__ x, const float* __restrict__ w,
                                                const float* __restrict__ bias, float* __restrict__ h1,
                                                const float* __restrict__ sc, unsigned* statsu) {
    int bc = blockIdx.x;
    int b = bc >> 8, c = bc & 255;
    __shared__ float tile[58 * 58];
    int tid = threadIdx.x;
    for (int i = tid; i < 58 * 58; i += 256) tile[i] = 0.f;   // zero pad
    __syncthreads();
    float mnx = sc[0], scx = sc[1];
    const float* px = x + (size_t)bc * HW;
    for (int p = tid; p < HW; p += 256) {
        int i = p / 56, j = p - i * 56;
        tile[(i + 1) * 58 + j + 1] = qz(px[p], mnx, scx);
    }
    __syncthreads();
    float qw[9];
    #pragma unroll
    for (int k = 0; k < 9; k++) qw[k] = qz(w[c * 9 + k], sc[2], sc[3]);
    float qb = qz(bias[c], sc[4], sc[5]);
    float* po = h1 + (size_t)bc * HW;
    float lmn = INFINITY, lmx = -INFINITY;
    for (int p = tid; p < HW; p += 256) {
        int i = p / 56, j = p - i * 56;
        const float* t = &tile[i * 58 + j];
        float acc = t[0] * qw[0] + t[1] * qw[1] + t[2] * qw[2]
                  + t[58] * qw[3] + t[59] * qw[4] + t[60] * qw[5]
                  + t[116] * qw[6] + t[117] * qw[7] + t[118] * qw[8];
        acc += qb;
        po[p] = acc;
        lmn = fminf(lmn, acc); lmx = fmaxf(lmx, acc);
    }
    blk_red_minmax(lmn, lmx);
    if (tid == 0) {
        atomicMin(&statsu[64 + b], enc(lmn));
        atomicMax(&statsu[96 + b], enc(lmx));
    }
}

__global__ void k_fin_slots(const unsigned* __restrict__ statsu, int mino, int maxo, float* sc, int off) {
    if (threadIdx.x == 0) {
        float sm = 0.f, sx = 0.f;
        for (int i = 0; i < 32; i++) { sm += dec(statsu[mino + i]); sx += dec(statsu[maxo + i]); }
        float m = sm / 32.f, X = sx / 32.f;
        sc[off] = m; sc[off + 1] = fmaxf((X - m) / 255.f, 1e-8f);
    }
}

// per-(channel,chunk) min/max/sum of quantized tensor. chunk = 2 batch samples.
__global__ __launch_bounds__(256) void k_chunk(const float* __restrict__ h, const float* __restrict__ sc,
                                               float* cmin, float* cmax, float* csum) {
    int ch = blockIdx.x >> 4, ck = blockIdx.x & 15;
    float mn0 = sc[0], s0 = sc[1];
    const float4* h4 = (const float4*)h;
    float mn = INFINITY, mx = -INFINITY, sum = 0.f;
    for (int e = threadIdx.x; e < 1568; e += 256) {       // 1568 float4 = 6272 floats
        int hi = (e >= 784) ? 1 : 0;
        int b = 2 * ck + hi;
        int pos = e - (hi ? 784 : 0);
        float4 v = h4[(size_t)(b * NCH + ch) * 784 + pos];
        float q0 = qz(v.x, mn0, s0), q1 = qz(v.y, mn0, s0);
        float q2 = qz(v.z, mn0, s0), q3 = qz(v.w, mn0, s0);
        mn = fminf(mn, fminf(fminf(q0, q1), fminf(q2, q3)));
        mx = fmaxf(mx, fmaxf(fmaxf(q0, q1), fmaxf(q2, q3)));
        sum += (q0 + q1) + (q2 + q3);
    }
    blk_red_minmax(mn, mx);
    sum = blk_red_sum(sum);
    if (threadIdx.x == 0) { cmin[blockIdx.x] = mn; cmax[blockIdx.x] = mx; csum[blockIdx.x] = sum; }
}

// per-channel RangeBN coefficients: a = q(scale)*q(bnw), m = mean
__global__ __launch_bounds__(256) void k_bnfin(const float* __restrict__ cmin, const float* __restrict__ cmax,
                                               const float* __restrict__ csum, const float* __restrict__ bnw,
                                               float* a, float* m) {
    int c = threadIdx.x;
    float mmax = 0.f, mmin = 0.f, sum = 0.f;
    for (int k = 0; k < 16; k++) { mmax += cmax[c * 16 + k]; mmin += cmin[c * 16 + k]; sum += csum[c * 16 + k]; }
    mmax *= 0.0625f; mmin *= 0.0625f;
    float mean = sum / 100352.f;
    const float scale_fix = (float)(0.175 * (1.0 + sqrt(3.14159265358979323846 * log(4.0))) / sqrt(2.0 * log(6272.0)));
    float scale = 1.f / ((mmax - mmin) * scale_fix + 1e-5f);
    __shared__ float r1[256], r2[256];
    r1[c] = scale; r2[c] = scale; __syncthreads();
    for (int s = 128; s > 0; s >>= 1) { if (c < s) { r1[c] = fminf(r1[c], r1[c + s]); r2[c] = fmaxf(r2[c], r2[c + s]); } __syncthreads(); }
    float smin = r1[0], smax = r2[0];
    __syncthreads();
    float w = bnw[c];
    r1[c] = w; r2[c] = w; __syncthreads();
    for (int s = 128; s > 0; s >>= 1) { if (c < s) { r1[c] = fminf(r1[c], r1[c + s]); r2[c] = fmaxf(r2[c], r2[c + s]); } __syncthreads(); }
    float wmin = r1[0], wmax = r2[0];
    float qs = qz(scale, smin, fmaxf((smax - smin) / 255.f, 1e-8f));
    float qw = qz(w, wmin, fmaxf((wmax - wmin) / 255.f, 1e-8f));
    a[c] = qs * qw; m[c] = mean;
}

// out = relu((qz(h)-m[c])*a[c] + bias[c]); optional fused per-sample min/max
__global__ __launch_bounds__(256) void k_bnapply(const float* __restrict__ h, const float* __restrict__ sc,
                                                 const float* __restrict__ a, const float* __restrict__ m,
                                                 const float* __restrict__ bias, float* __restrict__ out,
                                                 unsigned* slot_min, unsigned* slot_max) {
    int i4 = blockIdx.x * 256 + threadIdx.x;
    float4 v = ((const float4*)h)[i4];
    int lin = (i4 * 4) / HW;        // b*256 + c  (4 elems share it: HW%4==0)
    int c = lin & 255, b = lin >> 8;
    float mn = sc[0], s = sc[1], ac = a[c], mc = m[c], bc = bias[c];
    float o0 = fmaxf((qz(v.x, mn, s) - mc) * ac + bc, 0.f);
    float o1 = fmaxf((qz(v.y, mn, s) - mc) * ac + bc, 0.f);
    float o2 = fmaxf((qz(v.z, mn, s) - mc) * ac + bc, 0.f);
    float o3 = fmaxf((qz(v.w, mn, s) - mc) * ac + bc, 0.f);
    ((float4*)out)[i4] = make_float4(o0, o1, o2, o3);
    if (slot_min) {
        float lmn = fminf(fminf(o0, o1), fminf(o2, o3));
        float lmx = fmaxf(fmaxf(o0, o1), fmaxf(o2, o3));
        blk_red_minmax(lmn, lmx);
        if (threadIdx.x == 0) {
            atomicMin(&slot_min[b], enc(lmn));
            atomicMax(&slot_max[b], enc(lmx));
        }
    }
}

// pw-weight min/max (65536) + h2 quant scalars
__global__ void k_fin2(const float* __restrict__ pw, const unsigned* __restrict__ statsu, float* sc) {
    int tid = threadIdx.x;
    float mn = INFINITY, mx = -INFINITY;
    for (int i = tid; i < 65536; i += 256) { float v = pw[i]; mn = fminf(mn, v); mx = fmaxf(mx, v); }
    blk_red_minmax(mn, mx);
    if (tid == 0) {
        sc[10] = mn; sc[11] = fmaxf((mx - mn) / 255.f, 1e-8f);
        float sm = 0.f, sx = 0.f;
        for (int i = 0; i < 32; i++) { sm += dec(statsu[128 + i]); sx += dec(statsu[160 + i]); }
        float m = sm / 32.f, X = sx / 32.f;
        sc[8] = m; sc[9] = fmaxf((X - m) / 255.f, 1e-8f);
    }
}

// quantize pointwise weight, stored transposed: qwT[ci][co]
__global__ void k_qwT(const float* __restrict__ w, const float* __restrict__ sc, float* __restrict__ qwT) {
    int ci = blockIdx.x, co = threadIdx.x;
    qwT[ci * 256 + co] = qz(w[co * 256 + ci], sc[0], sc[1]);
}

// fp32 tiled GEMM per batch: out2[b,co,hw] = sum_ci qwT[ci][co]*qz(h2[b,ci,hw])
// grid (49 hw-tiles, 4 co-tiles, 32 b); 64x64 tile, 4x4 per thread, K-step 16
__global__ __launch_bounds__(256) void k_gemm(const float* __restrict__ h2, const float* __restrict__ qwT,
                                              const float* __restrict__ sc, float* __restrict__ out2,
                                              unsigned* slot_min, unsigned* slot_max) {
    int b = blockIdx.z, cot = blockIdx.y, hwt = blockIdx.x;
    __shared__ __align__(16) float As[16][64];
    __shared__ __align__(16) float Bs[16][64];
    int tid = threadIdx.x;
    int tx = tid & 15, ty = tid >> 4;
    int lc = tx * 4;
    float mn0 = sc[0], s0 = sc[1];
    float acc[4][4];
    #pragma unroll
    for (int i = 0; i < 4; i++)
        #pragma unroll
        for (int j = 0; j < 4; j++) acc[i][j] = 0.f;
    const float* hb = h2 + (size_t)b * SAMPLE + hwt * 64;
    for (int k0 = 0; k0 < 256; k0 += 16) {
        float4 av = *(const float4*)&qwT[(k0 + ty) * 256 + cot * 64 + lc];
        float4 bv = *(const float4*)&hb[(size_t)(k0 + ty) * HW + lc];
        bv.x = qz(bv.x, mn0, s0); bv.y = qz(bv.y, mn0, s0);
        bv.z = qz(bv.z, mn0, s0); bv.w = qz(bv.w, mn0, s0);
        *(float4*)&As[ty][lc] = av;
        *(float4*)&Bs[ty][lc] = bv;
        __syncthreads();
        #pragma unroll
        for (int kk = 0; kk < 16; kk++) {
            float4 a4 = *(const float4*)&As[kk][ty * 4];
            float4 b4 = *(const float4*)&Bs[kk][tx * 4];
            acc[0][0] += a4.x * b4.x; acc[0][1] += a4.x * b4.y; acc[0][2] += a4.x * b4.z; acc[0][3] += a4.x * b4.w;
            acc[1][0] += a4.y * b4.x; acc[1][1] += a4.y * b4.y; acc[1][2] += a4.y * b4.z; acc[1][3] += a4.y * b4.w;
            acc[2][0] += a4.z * b4.x; acc[2][1] += a4.z * b4.y; acc[2][2] += a4.z * b4.z; acc[2][3] += a4.z * b4.w;
            acc[3][0] += a4.w * b4.x; acc[3][1] += a4.w * b4.y; acc[3][2] += a4.w * b4.z; acc[3][3] += a4.w * b4.w;
        }
        __syncthreads();
    }
    float lmn = INFINITY, lmx = -INFINITY;
    float* ob = out2 + (size_t)b * SAMPLE + (size_t)(cot * 64 + ty * 4) * HW + hwt * 64 + tx * 4;
    #pragma unroll
    for (int ii = 0; ii < 4; ii++) {
        float4 v = make_float4(acc[ii][0], acc[ii][1], acc[ii][2], acc[ii][3]);
        *(float4*)&ob[(size_t)ii * HW] = v;
        lmn = fminf(lmn, fminf(fminf(v.x, v.y), fminf(v.z, v.w)));
        lmx = fmaxf(lmx, fmaxf(fmaxf(v.x, v.y), fmaxf(v.z, v.w)));
    }
    blk_red_minmax(lmn, lmx);
    if (tid == 0) {
        atomicMin(&slot_min[b], enc(lmn));
        atomicMax(&slot_max[b], enc(lmx));
    }
}

// ---------- launch ----------

extern "C" void kernel_launch(void* const* d_in, const int* in_sizes, int n_in,
                              void* d_out, int out_size, void* d_ws, size_t ws_size,
                              hipStream_t stream) {
    (void)in_sizes; (void)n_in; (void)out_size; (void)ws_size;
    const float* x    = (const float*)d_in[0];
    const float* dww  = (const float*)d_in[1];
    const float* dwb  = (const float*)d_in[2];
    const float* bn1w = (const float*)d_in[3];
    const float* bn1b = (const float*)d_in[4];
    const float* pww  = (const float*)d_in[5];
    const float* bn2w = (const float*)d_in[6];
    const float* bn2b = (const float*)d_in[7];

    float* buf1   = (float*)d_ws;            // h1, later out2
    float* buf2   = buf1 + TOT;              // h2
    float* qwT    = buf2 + TOT;              // 65536
    float* statsf = qwT + 65536;
    unsigned* statsu = (unsigned*)statsf;    // [0..255] encoded min/max slots
    float* sc   = statsf + 256;              // scalars
    float* cmin = statsf + 512;
    float* cmax = cmin + 4096;
    float* csum = cmax + 4096;
    float* a1 = csum + 4096; float* m1 = a1 + 256;
    float* a2 = m1 + 256;    float* m2 = a2 + 256;

    k_init<<<1, 256, 0, stream>>>(statsu);
    k_minmax_x<<<dim3(16, 32), 256, 0, stream>>>((const float4*)x, statsu);
    k_fin1<<<1, 256, 0, stream>>>(dww, dwb, statsu, sc);
    k_dwconv<<<NB * NCH, 256, 0, stream>>>(x, dww, dwb, buf1, sc, statsu);
    k_fin_slots<<<1, 64, 0, stream>>>(statsu, 64, 96, sc, 6);
    k_chunk<<<4096, 256, 0, stream>>>(buf1, sc + 6, cmin, cmax, csum);
    k_bnfin<<<1, 256, 0, stream>>>(cmin, cmax, csum, bn1w, a1, m1);
    k_bnapply<<<25088, 256, 0, stream>>>(buf1, sc + 6, a1, m1, bn1b, buf2, statsu + 128, statsu + 160);
    k_fin2<<<1, 256, 0, stream>>>(pww, statsu, sc);
    k_qwT<<<256, 256, 0, stream>>>(pww, sc + 10, qwT);
    k_gemm<<<dim3(49, 4, 32), 256, 0, stream>>>(buf2, qwT, sc + 8, buf1, statsu + 192, statsu + 224);
    k_fin_slots<<<1, 64, 0, stream>>>(statsu, 192, 224, sc, 12);
    k_chunk<<<4096, 256, 0, stream>>>(buf1, sc + 12, cmin, cmax, csum);
    k_bnfin<<<1, 256, 0, stream>>>(cmin, cmax, csum, bn2w, a2, m2);
    k_bnapply<<<25088, 256, 0, stream>>>(buf1, sc + 12, a2, m2, bn2b, (float*)d_out, nullptr, nullptr);
}

// Round 2
// 603.166 us; speedup vs baseline: 1.5286x; 1.5286x over previous
//
#include <hip/hip_runtime.h>
#include <math.h>

#define IMG 56
#define HW 3136          // 56*56
#define NCH 256
#define NB 32
#define SAMPLE (NCH*HW)  // 802816
#define TOT (NB*SAMPLE)  // 25690112

// ---------- helpers ----------

__device__ __forceinline__ float qz(float x, float mn, float scale) {
    float t = (x - mn) / scale;
    t = fminf(fmaxf(t, 0.f), 255.f);
    return rintf(t) * scale + mn;   // rintf = round-half-even, matches jnp.round
}

// order-preserving float<->uint encode for atomicMin/Max on floats
__device__ __forceinline__ unsigned enc(float f) {
    unsigned u = __float_as_uint(f);
    return (u & 0x80000000u) ? ~u : (u ^ 0x80000000u);
}
__device__ __forceinline__ float dec(unsigned u) {
    unsigned v = (u & 0x80000000u) ? (u ^ 0x80000000u) : ~u;
    return __uint_as_float(v);
}

// block-level min/max reduce (result valid on thread 0). blockDim must be mult of 64.
__device__ __forceinline__ void blk_red_minmax(float& mn, float& mx) {
    __shared__ float smn[4], smx[4];
    __syncthreads();   // protect shared reuse across successive calls
    #pragma unroll
    for (int o = 32; o > 0; o >>= 1) {
        mn = fminf(mn, __shfl_down(mn, o));
        mx = fmaxf(mx, __shfl_down(mx, o));
    }
    int lane = threadIdx.x & 63, w = threadIdx.x >> 6;
    if (lane == 0) { smn[w] = mn; smx[w] = mx; }
    __syncthreads();
    if (threadIdx.x == 0) {
        int nw = (int)blockDim.x >> 6;
        for (int i = 1; i < nw; i++) { mn = fminf(mn, smn[i]); mx = fmaxf(mx, smx[i]); }
    }
}

// result broadcast to all threads
__device__ __forceinline__ void blk_red_minmax_bcast(float& mn, float& mx) {
    __shared__ float bb[2];
    blk_red_minmax(mn, mx);
    if (threadIdx.x == 0) { bb[0] = mn; bb[1] = mx; }
    __syncthreads();
    mn = bb[0]; mx = bb[1];
}

__device__ __forceinline__ float blk_red_sum(float v) {
    __shared__ float ss[4];
    __syncthreads();
    #pragma unroll
    for (int o = 32; o > 0; o >>= 1) v += __shfl_down(v, o);
    int lane = threadIdx.x & 63, w = threadIdx.x >> 6;
    if (lane == 0) ss[w] = v;
    __syncthreads();
    if (threadIdx.x == 0) {
        int nw = (int)blockDim.x >> 6;
        for (int i = 1; i < nw; i++) v += ss[i];
    }
    return v;
}

// ---------- kernels ----------

// init stat slots: o2mn=+inf(enc), o2mx=-inf(enc=0), o2sum=0, xsl, pwsl
__global__ void k_init(unsigned* xsl, unsigned* pwsl, unsigned* o2mn, unsigned* o2mx, float* o2sum) {
    int i = blockIdx.x * 256 + threadIdx.x;   // grid 32 blocks -> 8192
    o2mn[i] = 0xFFFFFFFFu; o2mx[i] = 0u; o2sum[i] = 0.f;
    if (blockIdx.x == 0) {
        if (threadIdx.x < 64) xsl[threadIdx.x] = (threadIdx.x < 32) ? 0xFFFFFFFFu : 0u;
        if (threadIdx.x == 64) { pwsl[0] = 0xFFFFFFFFu; pwsl[1] = 0u; }
    }
}

// pointwise-weight global min/max (65536 elems), 64 blocks
__global__ __launch_bounds__(256) void k_pwmm(const float4* __restrict__ pw4, unsigned* pwsl) {
    int i = blockIdx.x * 256 + threadIdx.x;
    float4 v = pw4[i];
    float mn = fminf(fminf(v.x, v.y), fminf(v.z, v.w));
    float mx = fmaxf(fmaxf(v.x, v.y), fmaxf(v.z, v.w));
    blk_red_minmax(mn, mx);
    if (threadIdx.x == 0) { atomicMin(&pwsl[0], enc(mn)); atomicMax(&pwsl[1], enc(mx)); }
}

// per-sample min/max of x. grid (16 chunks, 32 samples)
__global__ __launch_bounds__(256) void k_minmax_x(const float4* __restrict__ x4, unsigned* xsl) {
    int b = blockIdx.y, blk = blockIdx.x;
    const float4* p = x4 + (size_t)b * 200704 + (size_t)blk * 12544;
    float mn = INFINITY, mx = -INFINITY;
    for (int k = threadIdx.x; k < 12544; k += 256) {
        float4 v = p[k];
        mn = fminf(mn, fminf(fminf(v.x, v.y), fminf(v.z, v.w)));
        mx = fmaxf(mx, fmaxf(fmaxf(v.x, v.y), fmaxf(v.z, v.w)));
    }
    blk_red_minmax(mn, mx);
    if (threadIdx.x == 0) {
        atomicMin(&xsl[b], enc(mn));
        atomicMax(&xsl[32 + b], enc(mx));
    }
}

// sc layout (float): 0 mn_x 1 s_x | 2 mn_w1 3 s_w1 | 4 mn_b1 5 s_b1 | 6 mn_h1 7 s_h1
//                    8 mn_h2 9 s_h2 | 10 mn_w2 11 s_w2 | 12 mn_o2 13 s_o2
__global__ void k_fin1(const float* __restrict__ dww, const float* __restrict__ dwb,
                       const unsigned* __restrict__ xsl, float* sc) {
    int tid = threadIdx.x;
    float mn = INFINITY, mx = -INFINITY;
    for (int i = tid; i < 2304; i += 256) { float v = dww[i]; mn = fminf(mn, v); mx = fmaxf(mx, v); }
    blk_red_minmax(mn, mx);
    float w1min = mn, w1max = mx;                 // valid on tid 0
    float v = dwb[tid]; mn = v; mx = v;
    blk_red_minmax(mn, mx);
    if (tid == 0) {
        float sm = 0.f, sx = 0.f;
        for (int i = 0; i < 32; i++) { sm += dec(xsl[i]); sx += dec(xsl[32 + i]); }
        float m = sm / 32.f, X = sx / 32.f;
        sc[0] = m;      sc[1] = fmaxf((X - m) / 255.f, 1e-8f);
        sc[2] = w1min;  sc[3] = fmaxf((w1max - w1min) / 255.f, 1e-8f);
        sc[4] = mn;     sc[5] = fmaxf((mx - mn) / 255.f, 1e-8f);
    }
}

// depthwise 3x3 pad=1 on quantized input/weight/bias; writes RAW h1 and
// per-(b,c) raw min/max/sum (direct stores, block bc == sample (b,c))
__global__ __launch_bounds__(256) void k_dwconv(const float* __restrict__ x, const float* __restrict__ w,
                                                const float* __restrict__ bias, float* __restrict__ h1,
                                                const float* __restrict__ sc,
                                                float* __restrict__ h1mn, float* __restrict__ h1mx,
                                                float* __restrict__ h1sm) {
    int bc = blockIdx.x;
    int c = bc & 255;
    __shared__ float tile[58 * 58];
    int tid = threadIdx.x;
    for (int i = tid; i < 58 * 58; i += 256) tile[i] = 0.f;   // zero pad
    __syncthreads();
    float mnx = sc[0], scx = sc[1];
    const float* px = x + (size_t)bc * HW;
    for (int p = tid; p < HW; p += 256) {
        int i = p / 56, j = p - i * 56;
        tile[(i + 1) * 58 + j + 1] = qz(px[p], mnx, scx);
    }
    __syncthreads();
    float qw[9];
    #pragma unroll
    for (int k = 0; k < 9; k++) qw[k] = qz(w[c * 9 + k], sc[2], sc[3]);
    float qb = qz(bias[c], sc[4], sc[5]);
    float* po = h1 + (size_t)bc * HW;
    float lmn = INFINITY, lmx = -INFINITY, lsum = 0.f;
    for (int p = tid; p < HW; p += 256) {
        int i = p / 56, j = p - i * 56;
        const float* t = &tile[i * 58 + j];
        float acc = t[0] * qw[0] + t[1] * qw[1] + t[2] * qw[2]
                  + t[58] * qw[3] + t[59] * qw[4] + t[60] * qw[5]
                  + t[116] * qw[6] + t[117] * qw[7] + t[118] * qw[8];
        acc += qb;
        po[p] = acc;
        lmn = fminf(lmn, acc); lmx = fmaxf(lmx, acc); lsum += acc;
    }
    blk_red_minmax(lmn, lmx);
    float ls = blk_red_sum(lsum);
    if (tid == 0) { h1mn[bc] = lmn; h1mx[bc] = lmx; h1sm[bc] = ls; }
}

// all h1-derived scalars/coeffs from per-(b,c) stats. Single block, 256 threads.
// Produces: sc[6..11]; P1[c]=s1*a1_c, Q1[c]=mn1*a1_c + (bn1b_c - m1_c*a1_c)
__global__ __launch_bounds__(256) void k_stats1(const float* __restrict__ h1mn, const float* __restrict__ h1mx,
                                                const float* __restrict__ h1sm,
                                                const float* __restrict__ bn1w, const float* __restrict__ bn1b,
                                                const unsigned* __restrict__ pwsl, float* sc,
                                                float* __restrict__ P1, float* __restrict__ Q1) {
    int tid = threadIdx.x;
    __shared__ float sp[2];
    // (a) h1 quant params: mean over b of per-sample min/max
    float amn = 0.f, amx = 0.f;
    for (int b = 0; b < 32; b++) {
        float mn = h1mn[b * 256 + tid], mx = h1mx[b * 256 + tid];
        blk_red_minmax(mn, mx);
        if (tid == 0) { amn += mn; amx += mx; }
    }
    if (tid == 0) {
        float m = amn / 32.f, X = amx / 32.f;
        sp[0] = m; sp[1] = fmaxf((X - m) / 255.f, 1e-8f);
        sc[6] = sp[0]; sc[7] = sp[1];
    }
    __syncthreads();
    float mn1 = sp[0], s1 = sp[1];
    // (b) per-channel RangeBN1 (thread = channel)
    int c = tid;
    float mmax = 0.f, mmin = 0.f, sum = 0.f;
    for (int ck = 0; ck < 16; ck++) {
        float c0n = h1mn[(2 * ck) * 256 + c], c1n = h1mn[(2 * ck + 1) * 256 + c];
        float c0x = h1mx[(2 * ck) * 256 + c], c1x = h1mx[(2 * ck + 1) * 256 + c];
        mmin += qz(fminf(c0n, c1n), mn1, s1);     // max/min commute with monotone qz
        mmax += qz(fmaxf(c0x, c1x), mn1, s1);
        sum  += h1sm[(2 * ck) * 256 + c] + h1sm[(2 * ck + 1) * 256 + c];
    }
    mmin *= 0.0625f; mmax *= 0.0625f;
    float mean = sum / 100352.f;   // raw-sum approx of quantized mean (err ~5e-5)
    const float scale_fix = (float)(0.175 * (1.0 + sqrt(3.14159265358979323846 * log(4.0))) / sqrt(2.0 * log(6272.0)));
    float scale = 1.f / ((mmax - mmin) * scale_fix + 1e-5f);
    float ssn = scale, ssx = scale;
    blk_red_minmax_bcast(ssn, ssx);
    float w = bn1w[c];
    float wmn = w, wmx = w;
    blk_red_minmax_bcast(wmn, wmx);
    float qs = qz(scale, ssn, fmaxf((ssx - ssn) / 255.f, 1e-8f));
    float qw = qz(w, wmn, fmaxf((wmx - wmn) / 255.f, 1e-8f));
    float a1 = qs * qw;                       // a1 > 0 (scale>0, bnw>0 after qz)
    float be = bn1b[c] - mean * a1;
    float p1v = s1 * a1, q1v = mn1 * a1 + be;
    P1[c] = p1v; Q1[c] = q1v;
    // (c) h2 per-sample min/max through monotone map -> h2 quant params
    float a2mn = 0.f, a2mx = 0.f;
    for (int b = 0; b < 32; b++) {
        float vn = h1mn[b * 256 + c], vx = h1mx[b * 256 + c];
        float hn = fmaxf(rintf(fminf(fmaxf((vn - mn1) / s1, 0.f), 255.f)) * p1v + q1v, 0.f);
        float hx = fmaxf(rintf(fminf(fmaxf((vx - mn1) / s1, 0.f), 255.f)) * p1v + q1v, 0.f);
        blk_red_minmax(hn, hx);
        if (tid == 0) { a2mn += hn; a2mx += hx; }
    }
    if (tid == 0) {
        float m = a2mn / 32.f, X = a2mx / 32.f;
        sc[8] = m; sc[9] = fmaxf((X - m) / 255.f, 1e-8f);
        float pmn = dec(pwsl[0]), pmx = dec(pwsl[1]);
        sc[10] = pmn; sc[11] = fmaxf((pmx - pmn) / 255.f, 1e-8f);
    }
}

// quantize pointwise weight, stored transposed: qwT[ci][co]
__global__ void k_qwT(const float* __restrict__ w, const float* __restrict__ sc, float* __restrict__ qwT) {
    int ci = blockIdx.x, co = threadIdx.x;
    qwT[ci * 256 + co] = qz(w[co * 256 + ci], sc[0], sc[1]);
}

// fp32 tiled GEMM per batch reading RAW h1; B-load applies qz->BN1->relu->qz.
// Epilogue: raw out2 + per-(b,co) min/max/sum via 16-lane shuffles + atomics.
__global__ __launch_bounds__(256) void k_gemm(const float* __restrict__ h1, const float* __restrict__ qwT,
                                              const float* __restrict__ sc,
                                              const float* __restrict__ P1, const float* __restrict__ Q1,
                                              float* __restrict__ out2,
                                              unsigned* o2mn, unsigned* o2mx, float* o2sum) {
    int b = blockIdx.z, cot = blockIdx.y, hwt = blockIdx.x;
    __shared__ __align__(16) float As[16][64];
    __shared__ __align__(16) float Bs[16][64];
    int tid = threadIdx.x;
    int tx = tid & 15, ty = tid >> 4;
    int lc = tx * 4;
    float mn1 = sc[6], s1 = sc[7], mn2 = sc[8], s2 = sc[9];
    float acc[4][4];
    #pragma unroll
    for (int i = 0; i < 4; i++)
        #pragma unroll
        for (int j = 0; j < 4; j++) acc[i][j] = 0.f;
    const float* hb = h1 + (size_t)b * SAMPLE + hwt * 64;
    for (int k0 = 0; k0 < 256; k0 += 16) {
        int ci = k0 + ty;
        float4 av = *(const float4*)&qwT[ci * 256 + cot * 64 + lc];
        float4 bv = *(const float4*)&hb[(size_t)ci * HW + lc];
        float p1 = P1[ci], q1 = Q1[ci];
        #pragma unroll
        for (int e = 0; e < 4; e++) {
            float v = (&bv.x)[e];
            float k1 = rintf(fminf(fmaxf((v - mn1) / s1, 0.f), 255.f));
            float h2 = fmaxf(k1 * p1 + q1, 0.f);
            float t2 = fminf(fmaxf((h2 - mn2) / s2, 0.f), 255.f);
            (&bv.x)[e] = rintf(t2) * s2 + mn2;
        }
        *(float4*)&As[ty][lc] = av;
        *(float4*)&Bs[ty][lc] = bv;
        __syncthreads();
        #pragma unroll
        for (int kk = 0; kk < 16; kk++) {
            float4 a4 = *(const float4*)&As[kk][ty * 4];
            float4 b4 = *(const float4*)&Bs[kk][tx * 4];
            acc[0][0] += a4.x * b4.x; acc[0][1] += a4.x * b4.y; acc[0][2] += a4.x * b4.z; acc[0][3] += a4.x * b4.w;
            acc[1][0] += a4.y * b4.x; acc[1][1] += a4.y * b4.y; acc[1][2] += a4.y * b4.z; acc[1][3] += a4.y * b4.w;
            acc[2][0] += a4.z * b4.x; acc[2][1] += a4.z * b4.y; acc[2][2] += a4.z * b4.z; acc[2][3] += a4.z * b4.w;
            acc[3][0] += a4.w * b4.x; acc[3][1] += a4.w * b4.y; acc[3][2] += a4.w * b4.z; acc[3][3] += a4.w * b4.w;
        }
        __syncthreads();
    }
    float* ob = out2 + (size_t)b * SAMPLE + (size_t)(cot * 64 + ty * 4) * HW + hwt * 64 + tx * 4;
    #pragma unroll
    for (int ii = 0; ii < 4; ii++) {
        float4 v = make_float4(acc[ii][0], acc[ii][1], acc[ii][2], acc[ii][3]);
        *(float4*)&ob[(size_t)ii * HW] = v;
        float lmn = fminf(fminf(v.x, v.y), fminf(v.z, v.w));
        float lmx = fmaxf(fmaxf(v.x, v.y), fmaxf(v.z, v.w));
        float lsm = (v.x + v.y) + (v.z + v.w);
        #pragma unroll
        for (int o = 1; o < 16; o <<= 1) {
            lmn = fminf(lmn, __shfl_xor(lmn, o));
            lmx = fmaxf(lmx, __shfl_xor(lmx, o));
            lsm += __shfl_xor(lsm, o);
        }
        if (tx == 0) {
            int idx = b * 256 + cot * 64 + ty * 4 + ii;
            atomicMin(&o2mn[idx], enc(lmn));
            atomicMax(&o2mx[idx], enc(lmx));
            atomicAdd(&o2sum[idx], lsm);
        }
    }
}

// out2-derived scalars/coeffs. P2[c]=s_o2*a2_c, Q2[c]=mn_o2*a2_c + (bn2b_c - m2_c*a2_c)
__global__ __launch_bounds__(256) void k_stats2(const unsigned* __restrict__ o2mnU, const unsigned* __restrict__ o2mxU,
                                                const float* __restrict__ o2sm,
                                                const float* __restrict__ bn2w, const float* __restrict__ bn2b,
                                                float* sc, float* __restrict__ P2, float* __restrict__ Q2) {
    int tid = threadIdx.x;
    __shared__ float sp[2];
    float amn = 0.f, amx = 0.f;
    for (int b = 0; b < 32; b++) {
        float mn = dec(o2mnU[b * 256 + tid]), mx = dec(o2mxU[b * 256 + tid]);
        blk_red_minmax(mn, mx);
        if (tid == 0) { amn += mn; amx += mx; }
    }
    if (tid == 0) {
        float m = amn / 32.f, X = amx / 32.f;
        sp[0] = m; sp[1] = fmaxf((X - m) / 255.f, 1e-8f);
        sc[12] = sp[0]; sc[13] = sp[1];
    }
    __syncthreads();
    float mno = sp[0], so = sp[1];
    int c = tid;
    float mmax = 0.f, mmin = 0.f, sum = 0.f;
    for (int ck = 0; ck < 16; ck++) {
        float c0n = dec(o2mnU[(2 * ck) * 256 + c]), c1n = dec(o2mnU[(2 * ck + 1) * 256 + c]);
        float c0x = dec(o2mxU[(2 * ck) * 256 + c]), c1x = dec(o2mxU[(2 * ck + 1) * 256 + c]);
        mmin += qz(fminf(c0n, c1n), mno, so);
        mmax += qz(fmaxf(c0x, c1x), mno, so);
        sum  += o2sm[(2 * ck) * 256 + c] + o2sm[(2 * ck + 1) * 256 + c];
    }
    mmin *= 0.0625f; mmax *= 0.0625f;
    float mean = sum / 100352.f;
    const float scale_fix = (float)(0.175 * (1.0 + sqrt(3.14159265358979323846 * log(4.0))) / sqrt(2.0 * log(6272.0)));
    float scale = 1.f / ((mmax - mmin) * scale_fix + 1e-5f);
    float ssn = scale, ssx = scale;
    blk_red_minmax_bcast(ssn, ssx);
    float w = bn2w[c];
    float wmn = w, wmx = w;
    blk_red_minmax_bcast(wmn, wmx);
    float qs = qz(scale, ssn, fmaxf((ssx - ssn) / 255.f, 1e-8f));
    float qw = qz(w, wmn, fmaxf((wmx - wmn) / 255.f, 1e-8f));
    float a2 = qs * qw;
    float be = bn2b[c] - mean * a2;
    P2[c] = so * a2; Q2[c] = mno * a2 + be;
}

// final: out = relu(rint(clamp((o2-mn)/s))*P2[c] + Q2[c]); 8 float4/thread for MLP
__global__ __launch_bounds__(256) void k_apply(const float4* __restrict__ o2, const float* __restrict__ sc,
                                               const float* __restrict__ P2, const float* __restrict__ Q2,
                                               float4* __restrict__ out) {
    int tid = threadIdx.x;
    int base = blockIdx.x * 2048 + tid;       // float4 index; grid 3136
    float mno = sc[12], so = sc[13];
    float4 v[8];
    #pragma unroll
    for (int j = 0; j < 8; j++) v[j] = o2[base + j * 256];
    #pragma unroll
    for (int j = 0; j < 8; j++) {
        int g = base + j * 256;
        int lin = (g * 4) / HW;               // float4 never straddles a (b,c) row
        int c = lin & 255;
        float p = P2[c], q = Q2[c];
        float4 r;
        r.x = fmaxf(rintf(fminf(fmaxf((v[j].x - mno) / so, 0.f), 255.f)) * p + q, 0.f);
        r.y = fmaxf(rintf(fminf(fmaxf((v[j].y - mno) / so, 0.f), 255.f)) * p + q, 0.f);
        r.z = fmaxf(rintf(fminf(fmaxf((v[j].z - mno) / so, 0.f), 255.f)) * p + q, 0.f);
        r.w = fmaxf(rintf(fminf(fmaxf((v[j].w - mno) / so, 0.f), 255.f)) * p + q, 0.f);
        out[base + j * 256] = r;
    }
}

// ---------- launch ----------

extern "C" void kernel_launch(void* const* d_in, const int* in_sizes, int n_in,
                              void* d_out, int out_size, void* d_ws, size_t ws_size,
                              hipStream_t stream) {
    (void)in_sizes; (void)n_in; (void)out_size; (void)ws_size;
    const float* x    = (const float*)d_in[0];
    const float* dww  = (const float*)d_in[1];
    const float* dwb  = (const float*)d_in[2];
    const float* bn1w = (const float*)d_in[3];
    const float* bn1b = (const float*)d_in[4];
    const float* pww  = (const float*)d_in[5];
    const float* bn2w = (const float*)d_in[6];
    const float* bn2b = (const float*)d_in[7];

    float* h1   = (float*)d_ws;              // TOT
    float* o2   = h1 + TOT;                  // TOT (raw pw-conv output)
    float* qwT  = o2 + TOT;                  // 65536
    float* sc   = qwT + 65536;               // 32 scalars
    unsigned* xsl  = (unsigned*)(sc + 32);   // 64
    unsigned* pwsl = xsl + 64;               // 2 (padded to 64)
    unsigned* o2mnU = pwsl + 64;             // 8192
    unsigned* o2mxU = o2mnU + 8192;          // 8192
    float* o2sm = (float*)(o2mxU + 8192);    // 8192
    float* h1mn = o2sm + 8192;               // 8192
    float* h1mx = h1mn + 8192;               // 8192
    float* h1sm = h1mx + 8192;               // 8192
    float* P1 = h1sm + 8192; float* Q1 = P1 + 256;
    float* P2 = Q1 + 256;    float* Q2 = P2 + 256;

    k_init<<<32, 256, 0, stream>>>(xsl, pwsl, o2mnU, o2mxU, o2sm);
    k_pwmm<<<64, 256, 0, stream>>>((const float4*)pww, pwsl);
    k_minmax_x<<<dim3(16, 32), 256, 0, stream>>>((const float4*)x, xsl);
    k_fin1<<<1, 256, 0, stream>>>(dww, dwb, xsl, sc);
    k_dwconv<<<NB * NCH, 256, 0, stream>>>(x, dww, dwb, h1, sc, h1mn, h1mx, h1sm);
    k_stats1<<<1, 256, 0, stream>>>(h1mn, h1mx, h1sm, bn1w, bn1b, pwsl, sc, P1, Q1);
    k_qwT<<<256, 256, 0, stream>>>(pww, sc + 10, qwT);
    k_gemm<<<dim3(49, 4, 32), 256, 0, stream>>>(h1, qwT, sc, P1, Q1, o2, o2mnU, o2mxU, o2sm);
    k_stats2<<<1, 256, 0, stream>>>(o2mnU, o2mxU, o2sm, bn2w, bn2b, sc, P2, Q2);
    k_apply<<<3136, 256, 0, stream>>>((const float4*)o2, sc, P2, Q2, (float4*)d_out);
}

// Round 3
// 481.094 us; speedup vs baseline: 1.9165x; 1.2537x over previous
//
#include <hip/hip_runtime.h>
#include <math.h>

#define IMG 56
#define HW 3136          // 56*56
#define NCH 256
#define NB 32
#define SAMPLE (NCH*HW)  // 802816
#define TOT (NB*SAMPLE)  // 25690112

typedef short s16x8 __attribute__((ext_vector_type(8)));
typedef float f32x4 __attribute__((ext_vector_type(4)));

// ---------- helpers ----------

__device__ __forceinline__ float qz(float x, float mn, float scale) {
    float t = (x - mn) / scale;
    t = fminf(fmaxf(t, 0.f), 255.f);
    return rintf(t) * scale + mn;   // rintf = round-half-even, matches jnp.round
}

__device__ __forceinline__ float codef(float x, float mn, float scale) {
    return rintf(fminf(fmaxf((x - mn) / scale, 0.f), 255.f));   // integer code 0..255
}

// exact bf16 bits for small non-negative integers (mantissa fits, no rounding)
__device__ __forceinline__ short bf16bits(float v) {
    return (short)(__float_as_uint(v) >> 16);
}

// order-preserving float<->uint encode for atomicMin/Max on floats
__device__ __forceinline__ unsigned enc(float f) {
    unsigned u = __float_as_uint(f);
    return (u & 0x80000000u) ? ~u : (u ^ 0x80000000u);
}
__device__ __forceinline__ float dec(unsigned u) {
    unsigned v = (u & 0x80000000u) ? (u ^ 0x80000000u) : ~u;
    return __uint_as_float(v);
}

// block-level min/max reduce (result valid on thread 0). blockDim must be mult of 64.
__device__ __forceinline__ void blk_red_minmax(float& mn, float& mx) {
    __shared__ float smn[4], smx[4];
    __syncthreads();
    #pragma unroll
    for (int o = 32; o > 0; o >>= 1) {
        mn = fminf(mn, __shfl_down(mn, o));
        mx = fmaxf(mx, __shfl_down(mx, o));
    }
    int lane = threadIdx.x & 63, w = threadIdx.x >> 6;
    if (lane == 0) { smn[w] = mn; smx[w] = mx; }
    __syncthreads();
    if (threadIdx.x == 0) {
        int nw = (int)blockDim.x >> 6;
        for (int i = 1; i < nw; i++) { mn = fminf(mn, smn[i]); mx = fmaxf(mx, smx[i]); }
    }
}

__device__ __forceinline__ void blk_red_minmax_bcast(float& mn, float& mx) {
    __shared__ float bb[2];
    blk_red_minmax(mn, mx);
    if (threadIdx.x == 0) { bb[0] = mn; bb[1] = mx; }
    __syncthreads();
    mn = bb[0]; mx = bb[1];
}

__device__ __forceinline__ float blk_red_sum(float v) {
    __shared__ float ss[4];
    __syncthreads();
    #pragma unroll
    for (int o = 32; o > 0; o >>= 1) v += __shfl_down(v, o);
    int lane = threadIdx.x & 63, w = threadIdx.x >> 6;
    if (lane == 0) ss[w] = v;
    __syncthreads();
    if (threadIdx.x == 0) {
        int nw = (int)blockDim.x >> 6;
        for (int i = 1; i < nw; i++) v += ss[i];
    }
    return v;
}

// ---------- kernels ----------

__global__ void k_init(unsigned* xsl, unsigned* pwsl, unsigned* o2mn, unsigned* o2mx, float* o2sum) {
    int i = blockIdx.x * 256 + threadIdx.x;   // grid 32 -> 8192
    o2mn[i] = 0xFFFFFFFFu; o2mx[i] = 0u; o2sum[i] = 0.f;
    if (blockIdx.x == 0) {
        if (threadIdx.x < 64) xsl[threadIdx.x] = (threadIdx.x < 32) ? 0xFFFFFFFFu : 0u;
        if (threadIdx.x == 64) { pwsl[0] = 0xFFFFFFFFu; pwsl[1] = 0u; }
    }
}

// pointwise-weight global min/max (65536 elems), 64 blocks
__global__ __launch_bounds__(256) void k_pwmm(const float4* __restrict__ pw4, unsigned* pwsl) {
    int i = blockIdx.x * 256 + threadIdx.x;
    float4 v = pw4[i];
    float mn = fminf(fminf(v.x, v.y), fminf(v.z, v.w));
    float mx = fmaxf(fmaxf(v.x, v.y), fmaxf(v.z, v.w));
    blk_red_minmax(mn, mx);
    if (threadIdx.x == 0) { atomicMin(&pwsl[0], enc(mn)); atomicMax(&pwsl[1], enc(mx)); }
}

// per-sample min/max of x. grid (16 chunks, 32 samples)
__global__ __launch_bounds__(256) void k_minmax_x(const float4* __restrict__ x4, unsigned* xsl) {
    int b = blockIdx.y, blk = blockIdx.x;
    const float4* p = x4 + (size_t)b * 200704 + (size_t)blk * 12544;
    float mn = INFINITY, mx = -INFINITY;
    for (int k = threadIdx.x; k < 12544; k += 256) {
        float4 v = p[k];
        mn = fminf(mn, fminf(fminf(v.x, v.y), fminf(v.z, v.w)));
        mx = fmaxf(mx, fmaxf(fmaxf(v.x, v.y), fmaxf(v.z, v.w)));
    }
    blk_red_minmax(mn, mx);
    if (threadIdx.x == 0) {
        atomicMin(&xsl[b], enc(mn));
        atomicMax(&xsl[32 + b], enc(mx));
    }
}

// sc layout: 0 mn_x 1 s_x | 2 mn_w1 3 s_w1 | 4 mn_b1 5 s_b1 | 6 mn_h1 7 s_h1
//            8 mn_h2 9 s_h2 | 10 mn_w2 11 s_w2 | 12 mn_o2 13 s_o2
__global__ void k_fin1(const float* __restrict__ dww, const float* __restrict__ dwb,
                       const unsigned* __restrict__ xsl, float* sc) {
    int tid = threadIdx.x;
    float mn = INFINITY, mx = -INFINITY;
    for (int i = tid; i < 2304; i += 256) { float v = dww[i]; mn = fminf(mn, v); mx = fmaxf(mx, v); }
    blk_red_minmax(mn, mx);
    float w1min = mn, w1max = mx;
    float v = dwb[tid]; mn = v; mx = v;
    blk_red_minmax(mn, mx);
    if (tid == 0) {
        float sm = 0.f, sx = 0.f;
        for (int i = 0; i < 32; i++) { sm += dec(xsl[i]); sx += dec(xsl[32 + i]); }
        float m = sm / 32.f, X = sx / 32.f;
        sc[0] = m;      sc[1] = fmaxf((X - m) / 255.f, 1e-8f);
        sc[2] = w1min;  sc[3] = fmaxf((w1max - w1min) / 255.f, 1e-8f);
        sc[4] = mn;     sc[5] = fmaxf((mx - mn) / 255.f, 1e-8f);
    }
}

// depthwise 3x3 pad=1; float4 staged LDS tile (stride 68, left pad 4), float4 outputs
__global__ __launch_bounds__(256) void k_dwconv(const float4* __restrict__ x4, const float* __restrict__ w,
                                                const float* __restrict__ bias, float* __restrict__ h1,
                                                const float* __restrict__ sc,
                                                float* __restrict__ h1mn, float* __restrict__ h1mx,
                                                float* __restrict__ h1sm) {
    int bc = blockIdx.x, c = bc & 255;
    __shared__ float tile[58 * 68];
    int tid = threadIdx.x;
    for (int i = tid; i < 58 * 68; i += 256) tile[i] = 0.f;
    __syncthreads();
    float mnx = sc[0], scx = sc[1];
    const float4* px = x4 + (size_t)bc * 784;
    #pragma unroll
    for (int it = 0; it < 4; it++) {
        int idx = it * 256 + tid;
        if (idx < 784) {
            int i = idx / 14, j = (idx - i * 14) * 4;
            float4 v = px[idx];
            v.x = qz(v.x, mnx, scx); v.y = qz(v.y, mnx, scx);
            v.z = qz(v.z, mnx, scx); v.w = qz(v.w, mnx, scx);
            *(float4*)&tile[(i + 1) * 68 + j + 4] = v;
        }
    }
    __syncthreads();
    float qw[9];
    #pragma unroll
    for (int k = 0; k < 9; k++) qw[k] = qz(w[c * 9 + k], sc[2], sc[3]);
    float qb = qz(bias[c], sc[4], sc[5]);
    float4* po = (float4*)(h1 + (size_t)bc * HW);
    float lmn = INFINITY, lmx = -INFINITY, lsum = 0.f;
    #pragma unroll
    for (int it = 0; it < 4; it++) {
        int idx = it * 256 + tid;
        if (idx < 784) {
            int i = idx / 14, j = (idx - i * 14) * 4;
            float o0 = qb, o1 = qb, o2v = qb, o3 = qb;
            #pragma unroll
            for (int r = 0; r < 3; r++) {
                const float* row = &tile[(i + r) * 68 + j + 3];
                float a0 = row[0];
                float4 mid = *(const float4*)&row[1];
                float a5 = row[5];
                float w0 = qw[3 * r], w1 = qw[3 * r + 1], w2 = qw[3 * r + 2];
                o0  += a0    * w0 + mid.x * w1 + mid.y * w2;
                o1  += mid.x * w0 + mid.y * w1 + mid.z * w2;
                o2v += mid.y * w0 + mid.z * w1 + mid.w * w2;
                o3  += mid.z * w0 + mid.w * w1 + a5    * w2;
            }
            po[idx] = make_float4(o0, o1, o2v, o3);
            lmn = fminf(lmn, fminf(fminf(o0, o1), fminf(o2v, o3)));
            lmx = fmaxf(lmx, fmaxf(fmaxf(o0, o1), fmaxf(o2v, o3)));
            lsum += (o0 + o1) + (o2v + o3);
        }
    }
    blk_red_minmax(lmn, lmx);
    float ls = blk_red_sum(lsum);
    if (tid == 0) { h1mn[bc] = lmn; h1mx[bc] = lmx; h1sm[bc] = ls; }
}

// all h1-derived scalars/coeffs. P1[c]=s1*a1_c, Q1[c]=mn1*a1_c + (bn1b_c - m1_c*a1_c)
__global__ __launch_bounds__(256) void k_stats1(const float* __restrict__ h1mn, const float* __restrict__ h1mx,
                                                const float* __restrict__ h1sm,
                                                const float* __restrict__ bn1w, const float* __restrict__ bn1b,
                                                const unsigned* __restrict__ pwsl, float* sc,
                                                float* __restrict__ P1, float* __restrict__ Q1) {
    int tid = threadIdx.x;
    __shared__ float sp[2];
    float amn = 0.f, amx = 0.f;
    for (int b = 0; b < 32; b++) {
        float mn = h1mn[b * 256 + tid], mx = h1mx[b * 256 + tid];
        blk_red_minmax(mn, mx);
        if (tid == 0) { amn += mn; amx += mx; }
    }
    if (tid == 0) {
        float m = amn / 32.f, X = amx / 32.f;
        sp[0] = m; sp[1] = fmaxf((X - m) / 255.f, 1e-8f);
        sc[6] = sp[0]; sc[7] = sp[1];
    }
    __syncthreads();
    float mn1 = sp[0], s1 = sp[1];
    int c = tid;
    float mmax = 0.f, mmin = 0.f, sum = 0.f;
    for (int ck = 0; ck < 16; ck++) {
        float c0n = h1mn[(2 * ck) * 256 + c], c1n = h1mn[(2 * ck + 1) * 256 + c];
        float c0x = h1mx[(2 * ck) * 256 + c], c1x = h1mx[(2 * ck + 1) * 256 + c];
        mmin += qz(fminf(c0n, c1n), mn1, s1);
        mmax += qz(fmaxf(c0x, c1x), mn1, s1);
        sum  += h1sm[(2 * ck) * 256 + c] + h1sm[(2 * ck + 1) * 256 + c];
    }
    mmin *= 0.0625f; mmax *= 0.0625f;
    float mean = sum / 100352.f;
    const float scale_fix = (float)(0.175 * (1.0 + sqrt(3.14159265358979323846 * log(4.0))) / sqrt(2.0 * log(6272.0)));
    float scale = 1.f / ((mmax - mmin) * scale_fix + 1e-5f);
    float ssn = scale, ssx = scale;
    blk_red_minmax_bcast(ssn, ssx);
    float w = bn1w[c];
    float wmn = w, wmx = w;
    blk_red_minmax_bcast(wmn, wmx);
    float qs = qz(scale, ssn, fmaxf((ssx - ssn) / 255.f, 1e-8f));
    float qw = qz(w, wmn, fmaxf((wmx - wmn) / 255.f, 1e-8f));
    float a1 = qs * qw;
    float be = bn1b[c] - mean * a1;
    float p1v = s1 * a1, q1v = mn1 * a1 + be;
    P1[c] = p1v; Q1[c] = q1v;
    float a2mn = 0.f, a2mx = 0.f;
    for (int b = 0; b < 32; b++) {
        float vn = h1mn[b * 256 + c], vx = h1mx[b * 256 + c];
        float hn = fmaxf(rintf(fminf(fmaxf((vn - mn1) / s1, 0.f), 255.f)) * p1v + q1v, 0.f);
        float hx = fmaxf(rintf(fminf(fmaxf((vx - mn1) / s1, 0.f), 255.f)) * p1v + q1v, 0.f);
        blk_red_minmax(hn, hx);
        if (tid == 0) { a2mn += hn; a2mx += hx; }
    }
    if (tid == 0) {
        float m = a2mn / 32.f, X = a2mx / 32.f;
        sc[8] = m; sc[9] = fmaxf((X - m) / 255.f, 1e-8f);
        float pmn = dec(pwsl[0]), pmx = dec(pwsl[1]);
        sc[10] = pmn; sc[11] = fmaxf((pmx - pmn) / 255.f, 1e-8f);
    }
}

// pw-weight integer codes (bf16 bits, layout [co][ci]) + per-co code sums
__global__ __launch_bounds__(256) void k_qw(const float* __restrict__ pw, const float* __restrict__ sc,
                                            short* __restrict__ wcodes, float* __restrict__ Wsum) {
    int co = blockIdx.x, ci = threadIdx.x;
    float kw = codef(pw[co * 256 + ci], sc[10], sc[11]);
    wcodes[co * 256 + ci] = bf16bits(kw);
    float s = blk_red_sum(kw);
    if (ci == 0) Wsum[co] = s;
}

// h1 -> h2 integer codes (bf16 bits), TRANSPOSED to [b][p][ci]; emits Bp[p]=sum_ci code
__global__ __launch_bounds__(256) void k_codes(const float* __restrict__ h1, const float* __restrict__ sc,
                                               const float* __restrict__ P1, const float* __restrict__ Q1,
                                               short* __restrict__ hcodes, float* __restrict__ Bp) {
    int b = blockIdx.y, p0 = blockIdx.x * 32;
    __shared__ float tile[256][33];
    __shared__ float psum[8][32];
    int tid = threadIdx.x;
    float mn1 = sc[6], s1 = sc[7], mn2 = sc[8], s2 = sc[9];
    int pl = tid & 31, cib = tid >> 5;
    float colpart = 0.f;
    for (int it = 0; it < 32; it++) {
        int ci = it * 8 + cib;
        float v = h1[((size_t)b * 256 + ci) * HW + p0 + pl];
        float k1 = rintf(fminf(fmaxf((v - mn1) / s1, 0.f), 255.f));
        float h2 = fmaxf(k1 * P1[ci] + Q1[ci], 0.f);
        float kb = rintf(fminf(fmaxf((h2 - mn2) / s2, 0.f), 255.f));
        tile[ci][pl] = kb;
        colpart += kb;
    }
    psum[cib][pl] = colpart;
    __syncthreads();
    if (tid < 32) {
        float s = 0.f;
        #pragma unroll
        for (int j = 0; j < 8; j++) s += psum[j][tid];
        Bp[(size_t)b * HW + p0 + tid] = s;
    }
    for (int it = 0; it < 32; it++) {
        float v = tile[tid][it];
        hcodes[((size_t)b * HW + p0 + it) * 256 + tid] = bf16bits(v);
    }
}

// MFMA GEMM on integer codes (exact): D[p,co] = sum_ci kb[p,ci]*kw[co,ci]
// o2 = a*D + b*W[co] + g*Bp[p] + d. Grid (49 p-tiles, 32 b), 256 thr = 4 waves.
__global__ __launch_bounds__(256) void k_gemm(const short* __restrict__ hcodes, const short* __restrict__ wcodes,
                                              const float* __restrict__ Wsum, const float* __restrict__ Bp,
                                              const float* __restrict__ sc, float* __restrict__ o2,
                                              unsigned* o2mn, unsigned* o2mx, float* o2sum) {
    int b = blockIdx.y, p0 = blockIdx.x * 64;
    __shared__ __align__(16) short As[64][40];    // [p][k], pad 32->40
    __shared__ __align__(16) short Bs[256][40];   // [co][k]
    __shared__ float T[4][64 * 17];               // per-wave transpose buffer
    int tid = threadIdx.x, lane = tid & 63, w = tid >> 6;
    int col = lane & 15, quad = lane >> 4;
    f32x4 acc[4][4];
    #pragma unroll
    for (int i = 0; i < 4; i++)
        #pragma unroll
        for (int j = 0; j < 4; j++) acc[i][j] = (f32x4){0.f, 0.f, 0.f, 0.f};
    int am = tid >> 2, akc = (tid & 3) * 8;
    const short* asrc = &hcodes[((size_t)b * HW + p0 + am) * 256 + akc];
    for (int k0 = 0; k0 < 256; k0 += 32) {
        *(s16x8*)&As[am][akc] = *(const s16x8*)(asrc + k0);
        #pragma unroll
        for (int jj = 0; jj < 4; jj++) {
            int idx = tid + 256 * jj, n = idx >> 2, kc = (idx & 3) * 8;
            *(s16x8*)&Bs[n][kc] = *(const s16x8*)&wcodes[n * 256 + k0 + kc];
        }
        __syncthreads();
        s16x8 af[4], bfr[4];
        #pragma unroll
        for (int mt = 0; mt < 4; mt++) af[mt] = *(const s16x8*)&As[mt * 16 + col][quad * 8];
        #pragma unroll
        for (int nt = 0; nt < 4; nt++) bfr[nt] = *(const s16x8*)&Bs[w * 64 + nt * 16 + col][quad * 8];
        #pragma unroll
        for (int mt = 0; mt < 4; mt++)
            #pragma unroll
            for (int nt = 0; nt < 4; nt++)
                acc[mt][nt] = __builtin_amdgcn_mfma_f32_16x16x32_bf16(af[mt], bfr[nt], acc[mt][nt], 0, 0, 0);
        __syncthreads();
    }
    float alpha = sc[11] * sc[9], beta = sc[11] * sc[8];
    float gamma = sc[10] * sc[9], delta = 256.f * sc[10] * sc[8];
    float Wv[4];
    #pragma unroll
    for (int nt = 0; nt < 4; nt++) Wv[nt] = Wsum[w * 64 + nt * 16 + col];
    float smn = INFINITY, smx = -INFINITY, ssum = 0.f;
    float* orow = o2 + ((size_t)b * 256 + w * 64 + lane) * HW + p0;
    for (int mt = 0; mt < 4; mt++) {
        float bpv[4];
        #pragma unroll
        for (int r = 0; r < 4; r++) bpv[r] = Bp[(size_t)b * HW + p0 + mt * 16 + quad * 4 + r];
        __syncthreads();
        #pragma unroll
        for (int nt = 0; nt < 4; nt++)
            #pragma unroll
            for (int r = 0; r < 4; r++)
                T[w][(nt * 16 + col) * 17 + quad * 4 + r] =
                    alpha * acc[mt][nt][r] + beta * Wv[nt] + gamma * bpv[r] + delta;
        __syncthreads();
        const float* row = &T[w][lane * 17];
        #pragma unroll
        for (int q4 = 0; q4 < 4; q4++) {
            float4 v = make_float4(row[q4 * 4], row[q4 * 4 + 1], row[q4 * 4 + 2], row[q4 * 4 + 3]);
            *(float4*)&orow[mt * 16 + q4 * 4] = v;
            smn = fminf(smn, fminf(fminf(v.x, v.y), fminf(v.z, v.w)));
            smx = fmaxf(smx, fmaxf(fmaxf(v.x, v.y), fmaxf(v.z, v.w)));
            ssum += (v.x + v.y) + (v.z + v.w);
        }
    }
    int sidx = b * 256 + w * 64 + lane;
    atomicMin(&o2mn[sidx], enc(smn));
    atomicMax(&o2mx[sidx], enc(smx));
    atomicAdd(&o2sum[sidx], ssum);
}

// out2-derived scalars/coeffs. P2[c]=s_o2*a2_c, Q2[c]=mn_o2*a2_c + (bn2b_c - m2_c*a2_c)
__global__ __launch_bounds__(256) void k_stats2(const unsigned* __restrict__ o2mnU, const unsigned* __restrict__ o2mxU,
                                                const float* __restrict__ o2sm,
                                                const float* __restrict__ bn2w, const float* __restrict__ bn2b,
                                                float* sc, float* __restrict__ P2, float* __restrict__ Q2) {
    int tid = threadIdx.x;
    __shared__ float sp[2];
    float amn = 0.f, amx = 0.f;
    for (int b = 0; b < 32; b++) {
        float mn = dec(o2mnU[b * 256 + tid]), mx = dec(o2mxU[b * 256 + tid]);
        blk_red_minmax(mn, mx);
        if (tid == 0) { amn += mn; amx += mx; }
    }
    if (tid == 0) {
        float m = amn / 32.f, X = amx / 32.f;
        sp[0] = m; sp[1] = fmaxf((X - m) / 255.f, 1e-8f);
        sc[12] = sp[0]; sc[13] = sp[1];
    }
    __syncthreads();
    float mno = sp[0], so = sp[1];
    int c = tid;
    float mmax = 0.f, mmin = 0.f, sum = 0.f;
    for (int ck = 0; ck < 16; ck++) {
        float c0n = dec(o2mnU[(2 * ck) * 256 + c]), c1n = dec(o2mnU[(2 * ck + 1) * 256 + c]);
        float c0x = dec(o2mxU[(2 * ck) * 256 + c]), c1x = dec(o2mxU[(2 * ck + 1) * 256 + c]);
        mmin += qz(fminf(c0n, c1n), mno, so);
        mmax += qz(fmaxf(c0x, c1x), mno, so);
        sum  += o2sm[(2 * ck) * 256 + c] + o2sm[(2 * ck + 1) * 256 + c];
    }
    mmin *= 0.0625f; mmax *= 0.0625f;
    float mean = sum / 100352.f;
    const float scale_fix = (float)(0.175 * (1.0 + sqrt(3.14159265358979323846 * log(4.0))) / sqrt(2.0 * log(6272.0)));
    float scale = 1.f / ((mmax - mmin) * scale_fix + 1e-5f);
    float ssn = scale, ssx = scale;
    blk_red_minmax_bcast(ssn, ssx);
    float w = bn2w[c];
    float wmn = w, wmx = w;
    blk_red_minmax_bcast(wmn, wmx);
    float qs = qz(scale, ssn, fmaxf((ssx - ssn) / 255.f, 1e-8f));
    float qw = qz(w, wmn, fmaxf((wmx - wmn) / 255.f, 1e-8f));
    float a2 = qs * qw;
    float be = bn2b[c] - mean * a2;
    P2[c] = so * a2; Q2[c] = mno * a2 + be;
}

// final: out = relu(rint(clamp((o2-mn)/s))*P2[c] + Q2[c]); 8 float4/thread
__global__ __launch_bounds__(256) void k_apply(const float4* __restrict__ o2, const float* __restrict__ sc,
                                               const float* __restrict__ P2, const float* __restrict__ Q2,
                                               float4* __restrict__ out) {
    int tid = threadIdx.x;
    int base = blockIdx.x * 2048 + tid;
    float mno = sc[12], so = sc[13];
    float4 v[8];
    #pragma unroll
    for (int j = 0; j < 8; j++) v[j] = o2[base + j * 256];
    #pragma unroll
    for (int j = 0; j < 8; j++) {
        int g = base + j * 256;
        int lin = (g * 4) / HW;
        int c = lin & 255;
        float p = P2[c], q = Q2[c];
        float4 r;
        r.x = fmaxf(rintf(fminf(fmaxf((v[j].x - mno) / so, 0.f), 255.f)) * p + q, 0.f);
        r.y = fmaxf(rintf(fminf(fmaxf((v[j].y - mno) / so, 0.f), 255.f)) * p + q, 0.f);
        r.z = fmaxf(rintf(fminf(fmaxf((v[j].z - mno) / so, 0.f), 255.f)) * p + q, 0.f);
        r.w = fmaxf(rintf(fminf(fmaxf((v[j].w - mno) / so, 0.f), 255.f)) * p + q, 0.f);
        out[base + j * 256] = r;
    }
}

// ---------- launch ----------

extern "C" void kernel_launch(void* const* d_in, const int* in_sizes, int n_in,
                              void* d_out, int out_size, void* d_ws, size_t ws_size,
                              hipStream_t stream) {
    (void)in_sizes; (void)n_in; (void)out_size; (void)ws_size;
    const float* x    = (const float*)d_in[0];
    const float* dww  = (const float*)d_in[1];
    const float* dwb  = (const float*)d_in[2];
    const float* bn1w = (const float*)d_in[3];
    const float* bn1b = (const float*)d_in[4];
    const float* pww  = (const float*)d_in[5];
    const float* bn2w = (const float*)d_in[6];
    const float* bn2b = (const float*)d_in[7];

    float* h1o2  = (float*)d_ws;                 // TOT floats: h1, later overwritten by o2
    short* hcodes = (short*)(h1o2 + TOT);        // TOT shorts (bf16 bits, [b][p][ci])
    float* after = (float*)(hcodes + TOT);
    short* wcodes = (short*)after;               // 65536 shorts
    float* Wsum  = after + 32768;                // 256
    float* Bp    = Wsum + 256;                   // 32*3136 = 100352
    float* sc    = Bp + 100352;                  // 32
    unsigned* xsl   = (unsigned*)(sc + 32);      // 64
    unsigned* pwsl  = xsl + 64;                  // 2 (padded 64)
    unsigned* o2mnU = pwsl + 64;                 // 8192
    unsigned* o2mxU = o2mnU + 8192;              // 8192
    float* o2sm = (float*)(o2mxU + 8192);        // 8192
    float* h1mn = o2sm + 8192;                   // 8192
    float* h1mx = h1mn + 8192;                   // 8192
    float* h1sm = h1mx + 8192;                   // 8192
    float* P1 = h1sm + 8192; float* Q1 = P1 + 256;
    float* P2 = Q1 + 256;    float* Q2 = P2 + 256;

    k_init<<<32, 256, 0, stream>>>(xsl, pwsl, o2mnU, o2mxU, o2sm);
    k_pwmm<<<64, 256, 0, stream>>>((const float4*)pww, pwsl);
    k_minmax_x<<<dim3(16, 32), 256, 0, stream>>>((const float4*)x, xsl);
    k_fin1<<<1, 256, 0, stream>>>(dww, dwb, xsl, sc);
    k_dwconv<<<NB * NCH, 256, 0, stream>>>((const float4*)x, dww, dwb, h1o2, sc, h1mn, h1mx, h1sm);
    k_stats1<<<1, 256, 0, stream>>>(h1mn, h1mx, h1sm, bn1w, bn1b, pwsl, sc, P1, Q1);
    k_qw<<<256, 256, 0, stream>>>(pww, sc, wcodes, Wsum);
    k_codes<<<dim3(98, 32), 256, 0, stream>>>(h1o2, sc, P1, Q1, hcodes, Bp);
    // o2 overwrites h1 buffer (h1 fully consumed by k_codes; stream-ordered safe)
    k_gemm<<<dim3(49, 32), 256, 0, stream>>>(hcodes, wcodes, Wsum, Bp, sc, h1o2, o2mnU, o2mxU, o2sm);
    k_stats2<<<1, 256, 0, stream>>>(o2mnU, o2mxU, o2sm, bn2w, bn2b, sc, P2, Q2);
    k_apply<<<3136, 256, 0, stream>>>((const float4*)h1o2, sc, P2, Q2, (float4*)d_out);
}

// Round 4
// 440.022 us; speedup vs baseline: 2.0953x; 1.0933x over previous
//
#include <hip/hip_runtime.h>
#include <math.h>

#define IMG 56
#define HW 3136          // 56*56
#define NCH 256
#define NB 32
#define SAMPLE (NCH*HW)  // 802816
#define TOT (NB*SAMPLE)  // 25690112

typedef short s16x8 __attribute__((ext_vector_type(8)));
typedef float f32x4 __attribute__((ext_vector_type(4)));

// ---------- helpers ----------

__device__ __forceinline__ float qz(float x, float mn, float scale) {
    float t = (x - mn) / scale;
    t = fminf(fmaxf(t, 0.f), 255.f);
    return rintf(t) * scale + mn;   // rintf = round-half-even, matches jnp.round
}

__device__ __forceinline__ float codef(float x, float mn, float scale) {
    return rintf(fminf(fmaxf((x - mn) / scale, 0.f), 255.f));   // integer code 0..255
}

// exact bf16 bits for small non-negative integers (mantissa fits, no rounding)
__device__ __forceinline__ unsigned bf16u(float v) {
    return (__float_as_uint(v) >> 16) & 0xFFFFu;
}

// order-preserving float<->uint encode for atomicMin/Max on floats
__device__ __forceinline__ unsigned enc(float f) {
    unsigned u = __float_as_uint(f);
    return (u & 0x80000000u) ? ~u : (u ^ 0x80000000u);
}
__device__ __forceinline__ float dec(unsigned u) {
    unsigned v = (u & 0x80000000u) ? (u ^ 0x80000000u) : ~u;
    return __uint_as_float(v);
}

// block-level min/max reduce (result valid on thread 0). blockDim must be mult of 64.
__device__ __forceinline__ void blk_red_minmax(float& mn, float& mx) {
    __shared__ float smn[4], smx[4];
    __syncthreads();
    #pragma unroll
    for (int o = 32; o > 0; o >>= 1) {
        mn = fminf(mn, __shfl_down(mn, o));
        mx = fmaxf(mx, __shfl_down(mx, o));
    }
    int lane = threadIdx.x & 63, w = threadIdx.x >> 6;
    if (lane == 0) { smn[w] = mn; smx[w] = mx; }
    __syncthreads();
    if (threadIdx.x == 0) {
        int nw = (int)blockDim.x >> 6;
        for (int i = 1; i < nw; i++) { mn = fminf(mn, smn[i]); mx = fmaxf(mx, smx[i]); }
    }
}

__device__ __forceinline__ void blk_red_minmax_bcast(float& mn, float& mx) {
    __shared__ float bb[2];
    blk_red_minmax(mn, mx);
    if (threadIdx.x == 0) { bb[0] = mn; bb[1] = mx; }
    __syncthreads();
    mn = bb[0]; mx = bb[1];
}

__device__ __forceinline__ float blk_red_sum(float v) {
    __shared__ float ss[4];
    __syncthreads();
    #pragma unroll
    for (int o = 32; o > 0; o >>= 1) v += __shfl_down(v, o);
    int lane = threadIdx.x & 63, w = threadIdx.x >> 6;
    if (lane == 0) ss[w] = v;
    __syncthreads();
    if (threadIdx.x == 0) {
        int nw = (int)blockDim.x >> 6;
        for (int i = 1; i < nw; i++) v += ss[i];
    }
    return v;
}

// ---------- kernels ----------

__global__ void k_init(unsigned* xsl, unsigned* pwsl, unsigned* o2mn, unsigned* o2mx, float* o2sum) {
    int i = blockIdx.x * 256 + threadIdx.x;   // grid 32 -> 8192
    o2mn[i] = 0xFFFFFFFFu; o2mx[i] = 0u; o2sum[i] = 0.f;
    if (blockIdx.x == 0) {
        if (threadIdx.x < 64) xsl[threadIdx.x] = (threadIdx.x < 32) ? 0xFFFFFFFFu : 0u;
        if (threadIdx.x == 64) { pwsl[0] = 0xFFFFFFFFu; pwsl[1] = 0u; }
    }
}

// pointwise-weight global min/max (65536 elems), 64 blocks
__global__ __launch_bounds__(256) void k_pwmm(const float4* __restrict__ pw4, unsigned* pwsl) {
    int i = blockIdx.x * 256 + threadIdx.x;
    float4 v = pw4[i];
    float mn = fminf(fminf(v.x, v.y), fminf(v.z, v.w));
    float mx = fmaxf(fmaxf(v.x, v.y), fmaxf(v.z, v.w));
    blk_red_minmax(mn, mx);
    if (threadIdx.x == 0) { atomicMin(&pwsl[0], enc(mn)); atomicMax(&pwsl[1], enc(mx)); }
}

// per-sample min/max of x. grid (16 chunks, 32 samples)
__global__ __launch_bounds__(256) void k_minmax_x(const float4* __restrict__ x4, unsigned* xsl) {
    int b = blockIdx.y, blk = blockIdx.x;
    const float4* p = x4 + (size_t)b * 200704 + (size_t)blk * 12544;
    float mn = INFINITY, mx = -INFINITY;
    for (int k = threadIdx.x; k < 12544; k += 256) {
        float4 v = p[k];
        mn = fminf(mn, fminf(fminf(v.x, v.y), fminf(v.z, v.w)));
        mx = fmaxf(mx, fmaxf(fmaxf(v.x, v.y), fmaxf(v.z, v.w)));
    }
    blk_red_minmax(mn, mx);
    if (threadIdx.x == 0) {
        atomicMin(&xsl[b], enc(mn));
        atomicMax(&xsl[32 + b], enc(mx));
    }
}

// sc layout: 0 mn_x 1 s_x | 2 mn_w1 3 s_w1 | 4 mn_b1 5 s_b1 | 6 mn_h1 7 s_h1
//            8 mn_h2 9 s_h2 | 10 mn_w2 11 s_w2 | 12 mn_o2 13 s_o2
__global__ void k_fin1(const float* __restrict__ dww, const float* __restrict__ dwb,
                       const unsigned* __restrict__ xsl, float* sc) {
    int tid = threadIdx.x;
    float mn = INFINITY, mx = -INFINITY;
    for (int i = tid; i < 2304; i += 256) { float v = dww[i]; mn = fminf(mn, v); mx = fmaxf(mx, v); }
    blk_red_minmax(mn, mx);
    float w1min = mn, w1max = mx;
    float v = dwb[tid]; mn = v; mx = v;
    blk_red_minmax(mn, mx);
    if (tid == 0) {
        float sm = 0.f, sx = 0.f;
        for (int i = 0; i < 32; i++) { sm += dec(xsl[i]); sx += dec(xsl[32 + i]); }
        float m = sm / 32.f, X = sx / 32.f;
        sc[0] = m;      sc[1] = fmaxf((X - m) / 255.f, 1e-8f);
        sc[2] = w1min;  sc[3] = fmaxf((w1max - w1min) / 255.f, 1e-8f);
        sc[4] = mn;     sc[5] = fmaxf((mx - mn) / 255.f, 1e-8f);
    }
}

// depthwise 3x3 pad=1; float4 staged LDS tile (stride 68, left pad 4), float4 outputs
__global__ __launch_bounds__(256) void k_dwconv(const float4* __restrict__ x4, const float* __restrict__ w,
                                                const float* __restrict__ bias, float* __restrict__ h1,
                                                const float* __restrict__ sc,
                                                float* __restrict__ h1mn, float* __restrict__ h1mx,
                                                float* __restrict__ h1sm) {
    int bc = blockIdx.x, c = bc & 255;
    __shared__ float tile[58 * 68];
    int tid = threadIdx.x;
    for (int i = tid; i < 58 * 68; i += 256) tile[i] = 0.f;
    __syncthreads();
    float mnx = sc[0], scx = sc[1];
    const float4* px = x4 + (size_t)bc * 784;
    #pragma unroll
    for (int it = 0; it < 4; it++) {
        int idx = it * 256 + tid;
        if (idx < 784) {
            int i = idx / 14, j = (idx - i * 14) * 4;
            float4 v = px[idx];
            v.x = qz(v.x, mnx, scx); v.y = qz(v.y, mnx, scx);
            v.z = qz(v.z, mnx, scx); v.w = qz(v.w, mnx, scx);
            *(float4*)&tile[(i + 1) * 68 + j + 4] = v;
        }
    }
    __syncthreads();
    float qw[9];
    #pragma unroll
    for (int k = 0; k < 9; k++) qw[k] = qz(w[c * 9 + k], sc[2], sc[3]);
    float qb = qz(bias[c], sc[4], sc[5]);
    float4* po = (float4*)(h1 + (size_t)bc * HW);
    float lmn = INFINITY, lmx = -INFINITY, lsum = 0.f;
    #pragma unroll
    for (int it = 0; it < 4; it++) {
        int idx = it * 256 + tid;
        if (idx < 784) {
            int i = idx / 14, j = (idx - i * 14) * 4;
            float o0 = qb, o1 = qb, o2v = qb, o3 = qb;
            #pragma unroll
            for (int r = 0; r < 3; r++) {
                const float* row = &tile[(i + r) * 68 + j + 3];
                float a0 = row[0];
                float4 mid = *(const float4*)&row[1];
                float a5 = row[5];
                float w0 = qw[3 * r], w1 = qw[3 * r + 1], w2 = qw[3 * r + 2];
                o0  += a0    * w0 + mid.x * w1 + mid.y * w2;
                o1  += mid.x * w0 + mid.y * w1 + mid.z * w2;
                o2v += mid.y * w0 + mid.z * w1 + mid.w * w2;
                o3  += mid.z * w0 + mid.w * w1 + a5    * w2;
            }
            po[idx] = make_float4(o0, o1, o2v, o3);
            lmn = fminf(lmn, fminf(fminf(o0, o1), fminf(o2v, o3)));
            lmx = fmaxf(lmx, fmaxf(fmaxf(o0, o1), fmaxf(o2v, o3)));
            lsum += (o0 + o1) + (o2v + o3);
        }
    }
    blk_red_minmax(lmn, lmx);
    float ls = blk_red_sum(lsum);
    if (tid == 0) { h1mn[bc] = lmn; h1mx[bc] = lmx; h1sm[bc] = ls; }
}

// all h1-derived scalars/coeffs. P1[c]=s1*a1_c, Q1[c]=mn1*a1_c + (bn1b_c - m1_c*a1_c)
__global__ __launch_bounds__(256) void k_stats1(const float* __restrict__ h1mn, const float* __restrict__ h1mx,
                                                const float* __restrict__ h1sm,
                                                const float* __restrict__ bn1w, const float* __restrict__ bn1b,
                                                const unsigned* __restrict__ pwsl, float* sc,
                                                float* __restrict__ P1, float* __restrict__ Q1) {
    int tid = threadIdx.x;
    __shared__ float sp[2];
    float amn = 0.f, amx = 0.f;
    for (int b = 0; b < 32; b++) {
        float mn = h1mn[b * 256 + tid], mx = h1mx[b * 256 + tid];
        blk_red_minmax(mn, mx);
        if (tid == 0) { amn += mn; amx += mx; }
    }
    if (tid == 0) {
        float m = amn / 32.f, X = amx / 32.f;
        sp[0] = m; sp[1] = fmaxf((X - m) / 255.f, 1e-8f);
        sc[6] = sp[0]; sc[7] = sp[1];
    }
    __syncthreads();
    float mn1 = sp[0], s1 = sp[1];
    int c = tid;
    float mmax = 0.f, mmin = 0.f, sum = 0.f;
    for (int ck = 0; ck < 16; ck++) {
        float c0n = h1mn[(2 * ck) * 256 + c], c1n = h1mn[(2 * ck + 1) * 256 + c];
        float c0x = h1mx[(2 * ck) * 256 + c], c1x = h1mx[(2 * ck + 1) * 256 + c];
        mmin += qz(fminf(c0n, c1n), mn1, s1);
        mmax += qz(fmaxf(c0x, c1x), mn1, s1);
        sum  += h1sm[(2 * ck) * 256 + c] + h1sm[(2 * ck + 1) * 256 + c];
    }
    mmin *= 0.0625f; mmax *= 0.0625f;
    float mean = sum / 100352.f;
    const float scale_fix = (float)(0.175 * (1.0 + sqrt(3.14159265358979323846 * log(4.0))) / sqrt(2.0 * log(6272.0)));
    float scale = 1.f / ((mmax - mmin) * scale_fix + 1e-5f);
    float ssn = scale, ssx = scale;
    blk_red_minmax_bcast(ssn, ssx);
    float w = bn1w[c];
    float wmn = w, wmx = w;
    blk_red_minmax_bcast(wmn, wmx);
    float qs = qz(scale, ssn, fmaxf((ssx - ssn) / 255.f, 1e-8f));
    float qw = qz(w, wmn, fmaxf((wmx - wmn) / 255.f, 1e-8f));
    float a1 = qs * qw;
    float be = bn1b[c] - mean * a1;
    float p1v = s1 * a1, q1v = mn1 * a1 + be;
    P1[c] = p1v; Q1[c] = q1v;
    float a2mn = 0.f, a2mx = 0.f;
    for (int b = 0; b < 32; b++) {
        float vn = h1mn[b * 256 + c], vx = h1mx[b * 256 + c];
        float hn = fmaxf(rintf(fminf(fmaxf((vn - mn1) / s1, 0.f), 255.f)) * p1v + q1v, 0.f);
        float hx = fmaxf(rintf(fminf(fmaxf((vx - mn1) / s1, 0.f), 255.f)) * p1v + q1v, 0.f);
        blk_red_minmax(hn, hx);
        if (tid == 0) { a2mn += hn; a2mx += hx; }
    }
    if (tid == 0) {
        float m = a2mn / 32.f, X = a2mx / 32.f;
        sc[8] = m; sc[9] = fmaxf((X - m) / 255.f, 1e-8f);
        float pmn = dec(pwsl[0]), pmx = dec(pwsl[1]);
        sc[10] = pmn; sc[11] = fmaxf((pmx - pmn) / 255.f, 1e-8f);
    }
}

// pw-weight integer codes (bf16 bits, layout [co][ci], K-contiguous) + per-co code sums
__global__ __launch_bounds__(256) void k_qw(const float* __restrict__ pw, const float* __restrict__ sc,
                                            short* __restrict__ wcodes, float* __restrict__ Wsum) {
    int co = blockIdx.x, ci = threadIdx.x;
    float kw = codef(pw[co * 256 + ci], sc[10], sc[11]);
    wcodes[co * 256 + ci] = (short)bf16u(kw);
    float s = blk_red_sum(kw);
    if (ci == 0) Wsum[co] = s;
}

// Fused codes+MFMA GEMM on integer codes (exact): D[p,co] = sum_ci kb[p,ci]*kw[co,ci]
// Reads RAW h1 [b][ci][p]; converts to codes in-register; Bp accumulated in LDS.
// o2 layout [b][p][co]. Grid (49 p-tiles, 32 b), 256 thr = 4 waves.
__global__ __launch_bounds__(256) void k_gemm(const float* __restrict__ h1, const short* __restrict__ wcodes,
                                              const float* __restrict__ Wsum, const float* __restrict__ sc,
                                              const float* __restrict__ P1, const float* __restrict__ Q1,
                                              float* __restrict__ o2,
                                              unsigned* o2mn, unsigned* o2mx, float* o2sum) {
    int b = blockIdx.y, p0 = blockIdx.x * 64;
    __shared__ unsigned AsU[64][20];   // [p][c2] packed 2 bf16 codes; stride 20 dwords (16B-aligned rows)
    __shared__ float BpP[16][64];      // per-c2 partial column sums
    __shared__ float BpT[64];
    int tid = threadIdx.x, lane = tid & 63, w = tid >> 6;
    int col = lane & 15, quad = lane >> 4;
    int c2 = tid >> 4, pq = tid & 15;  // staging role: rows ci=2*c2,2*c2+1; p-chunk pq*4
    float mn1 = sc[6], s1 = sc[7], mn2 = sc[8], s2 = sc[9];
    f32x4 acc[4][4];
    #pragma unroll
    for (int i = 0; i < 4; i++)
        #pragma unroll
        for (int j = 0; j < 4; j++) acc[i][j] = (f32x4){0.f, 0.f, 0.f, 0.f};
    float bp[4] = {0.f, 0.f, 0.f, 0.f};
    const float* arow = h1 + ((size_t)b * 256 + 2 * c2) * HW + p0 + pq * 4;
    const short* wbase = wcodes + ((size_t)(w * 64 + col)) * 256 + quad * 8;
    float4 v0 = *(const float4*)arow;
    float4 v1 = *(const float4*)(arow + HW);
    for (int k0 = 0; k0 < 256; k0 += 32) {
        float p1a = P1[k0 + 2 * c2], q1a = Q1[k0 + 2 * c2];
        float p1b = P1[k0 + 2 * c2 + 1], q1b = Q1[k0 + 2 * c2 + 1];
        unsigned pk[4];
        #pragma unroll
        for (int j = 0; j < 4; j++) {
            float va = (&v0.x)[j], vb = (&v1.x)[j];
            float k1a = rintf(fminf(fmaxf((va - mn1) / s1, 0.f), 255.f));
            float h2a = fmaxf(k1a * p1a + q1a, 0.f);
            float ka  = rintf(fminf(fmaxf((h2a - mn2) / s2, 0.f), 255.f));
            float k1b = rintf(fminf(fmaxf((vb - mn1) / s1, 0.f), 255.f));
            float h2b = fmaxf(k1b * p1b + q1b, 0.f);
            float kb  = rintf(fminf(fmaxf((h2b - mn2) / s2, 0.f), 255.f));
            bp[j] += ka + kb;
            pk[j] = bf16u(ka) | (bf16u(kb) << 16);
        }
        __syncthreads();   // previous iter's frag reads done
        #pragma unroll
        for (int j = 0; j < 4; j++) AsU[pq * 4 + j][c2] = pk[j];
        __syncthreads();
        if (k0 + 32 < 256) {   // prefetch next A-rows
            v0 = *(const float4*)(arow + (size_t)(k0 + 32) * HW);
            v1 = *(const float4*)(arow + (size_t)(k0 + 33) * HW);
        }
        s16x8 af[4], bfr[4];
        #pragma unroll
        for (int mt = 0; mt < 4; mt++) af[mt] = *(const s16x8*)&AsU[mt * 16 + col][quad * 4];
        #pragma unroll
        for (int nt = 0; nt < 4; nt++) bfr[nt] = *(const s16x8*)&wbase[(size_t)nt * 16 * 256 + k0];
        #pragma unroll
        for (int mt = 0; mt < 4; mt++)
            #pragma unroll
            for (int nt = 0; nt < 4; nt++)
                acc[mt][nt] = __builtin_amdgcn_mfma_f32_16x16x32_bf16(af[mt], bfr[nt], acc[mt][nt], 0, 0, 0);
    }
    // finalize Bp for this p-tile (in LDS, no global round-trip)
    #pragma unroll
    for (int j = 0; j < 4; j++) BpP[c2][pq * 4 + j] = bp[j];
    __syncthreads();
    if (tid < 64) {
        float s = 0.f;
        #pragma unroll
        for (int i = 0; i < 16; i++) s += BpP[i][tid];
        BpT[tid] = s;
    }
    __syncthreads();
    float alpha = sc[11] * sc[9];            // sw*s2   (D coeff)
    float beta  = sc[11] * sc[8];            // sw*mn2  (W[co] coeff)
    float gamma = sc[10] * sc[9];            // mnw*s2  (Bp coeff)
    float delta = 256.f * sc[10] * sc[8];    // 256*mnw*mn2
    float Wv[4];
    #pragma unroll
    for (int nt = 0; nt < 4; nt++) Wv[nt] = Wsum[w * 64 + nt * 16 + col];
    float snn[4], sxx[4], ssm[4];
    #pragma unroll
    for (int nt = 0; nt < 4; nt++) { snn[nt] = INFINITY; sxx[nt] = -INFINITY; ssm[nt] = 0.f; }
    float* obase = o2 + ((size_t)b * HW + p0) * 256 + w * 64 + col;
    #pragma unroll
    for (int mt = 0; mt < 4; mt++) {
        float bp4[4];
        #pragma unroll
        for (int r = 0; r < 4; r++) bp4[r] = BpT[mt * 16 + quad * 4 + r];
        #pragma unroll
        for (int nt = 0; nt < 4; nt++) {
            float wterm = beta * Wv[nt] + delta;
            #pragma unroll
            for (int r = 0; r < 4; r++) {
                float val = alpha * acc[mt][nt][r] + gamma * bp4[r] + wterm;
                obase[(size_t)(mt * 16 + quad * 4 + r) * 256 + nt * 16] = val;
                snn[nt] = fminf(snn[nt], val);
                sxx[nt] = fmaxf(sxx[nt], val);
                ssm[nt] += val;
            }
        }
    }
    #pragma unroll
    for (int nt = 0; nt < 4; nt++) {
        snn[nt] = fminf(snn[nt], __shfl_xor(snn[nt], 16));
        sxx[nt] = fmaxf(sxx[nt], __shfl_xor(sxx[nt], 16));
        ssm[nt] += __shfl_xor(ssm[nt], 16);
        snn[nt] = fminf(snn[nt], __shfl_xor(snn[nt], 32));
        sxx[nt] = fmaxf(sxx[nt], __shfl_xor(sxx[nt], 32));
        ssm[nt] += __shfl_xor(ssm[nt], 32);
    }
    if (lane < 16) {
        #pragma unroll
        for (int nt = 0; nt < 4; nt++) {
            int idx = b * 256 + w * 64 + nt * 16 + lane;
            atomicMin(&o2mn[idx], enc(snn[nt]));
            atomicMax(&o2mx[idx], enc(sxx[nt]));
            atomicAdd(&o2sum[idx], ssm[nt]);
        }
    }
}

// out2-derived scalars/coeffs. P2[c]=s_o2*a2_c, Q2[c]=mn_o2*a2_c + (bn2b_c - m2_c*a2_c)
__global__ __launch_bounds__(256) void k_stats2(const unsigned* __restrict__ o2mnU, const unsigned* __restrict__ o2mxU,
                                                const float* __restrict__ o2sm,
                                                const float* __restrict__ bn2w, const float* __restrict__ bn2b,
                                                float* sc, float* __restrict__ P2, float* __restrict__ Q2) {
    int tid = threadIdx.x;
    __shared__ float sp[2];
    float amn = 0.f, amx = 0.f;
    for (int b = 0; b < 32; b++) {
        float mn = dec(o2mnU[b * 256 + tid]), mx = dec(o2mxU[b * 256 + tid]);
        blk_red_minmax(mn, mx);
        if (tid == 0) { amn += mn; amx += mx; }
    }
    if (tid == 0) {
        float m = amn / 32.f, X = amx / 32.f;
        sp[0] = m; sp[1] = fmaxf((X - m) / 255.f, 1e-8f);
        sc[12] = sp[0]; sc[13] = sp[1];
    }
    __syncthreads();
    float mno = sp[0], so = sp[1];
    int c = tid;
    float mmax = 0.f, mmin = 0.f, sum = 0.f;
    for (int ck = 0; ck < 16; ck++) {
        float c0n = dec(o2mnU[(2 * ck) * 256 + c]), c1n = dec(o2mnU[(2 * ck + 1) * 256 + c]);
        float c0x = dec(o2mxU[(2 * ck) * 256 + c]), c1x = dec(o2mxU[(2 * ck + 1) * 256 + c]);
        mmin += qz(fminf(c0n, c1n), mno, so);
        mmax += qz(fmaxf(c0x, c1x), mno, so);
        sum  += o2sm[(2 * ck) * 256 + c] + o2sm[(2 * ck + 1) * 256 + c];
    }
    mmin *= 0.0625f; mmax *= 0.0625f;
    float mean = sum / 100352.f;
    const float scale_fix = (float)(0.175 * (1.0 + sqrt(3.14159265358979323846 * log(4.0))) / sqrt(2.0 * log(6272.0)));
    float scale = 1.f / ((mmax - mmin) * scale_fix + 1e-5f);
    float ssn = scale, ssx = scale;
    blk_red_minmax_bcast(ssn, ssx);
    float w = bn2w[c];
    float wmn = w, wmx = w;
    blk_red_minmax_bcast(wmn, wmx);
    float qs = qz(scale, ssn, fmaxf((ssx - ssn) / 255.f, 1e-8f));
    float qw = qz(w, wmn, fmaxf((wmx - wmn) / 255.f, 1e-8f));
    float a2 = qs * qw;
    float be = bn2b[c] - mean * a2;
    P2[c] = so * a2; Q2[c] = mno * a2 + be;
}

// final: transpose [b][p][co] -> NCHW [b][co][p] via LDS tile, map applied on write side
__global__ __launch_bounds__(256) void k_apply(const float* __restrict__ o2, const float* __restrict__ sc,
                                               const float* __restrict__ P2, const float* __restrict__ Q2,
                                               float* __restrict__ out) {
    __shared__ float tile[64][65];
    int b = blockIdx.z, p0 = blockIdx.x * 64, co0 = blockIdx.y * 64;
    int t = threadIdx.x, rr = t >> 4, cq = t & 15;
    float mno = sc[12], so = sc[13];
    #pragma unroll
    for (int it = 0; it < 4; it++) {
        int p = rr + 16 * it;
        float4 v = *(const float4*)&o2[((size_t)b * HW + p0 + p) * 256 + co0 + cq * 4];
        *(float4*)&tile[p][cq * 4] = v;
    }
    __syncthreads();
    #pragma unroll
    for (int it = 0; it < 4; it++) {
        int col = rr + 16 * it;             // local co
        int c = co0 + col;
        float pv = P2[c], qv = Q2[c];
        float4 r;
        #pragma unroll
        for (int j = 0; j < 4; j++) {
            float val = tile[cq * 4 + j][col];
            (&r.x)[j] = fmaxf(rintf(fminf(fmaxf((val - mno) / so, 0.f), 255.f)) * pv + qv, 0.f);
        }
        *(float4*)&out[((size_t)b * 256 + c) * HW + p0 + cq * 4] = r;
    }
}

// ---------- launch ----------

extern "C" void kernel_launch(void* const* d_in, const int* in_sizes, int n_in,
                              void* d_out, int out_size, void* d_ws, size_t ws_size,
                              hipStream_t stream) {
    (void)in_sizes; (void)n_in; (void)out_size; (void)ws_size;
    const float* x    = (const float*)d_in[0];
    const float* dww  = (const float*)d_in[1];
    const float* dwb  = (const float*)d_in[2];
    const float* bn1w = (const float*)d_in[3];
    const float* bn1b = (const float*)d_in[4];
    const float* pww  = (const float*)d_in[5];
    const float* bn2w = (const float*)d_in[6];
    const float* bn2b = (const float*)d_in[7];

    float* h1   = (float*)d_ws;                  // TOT  [b][ci][p]
    float* o2   = h1 + TOT;                      // TOT  [b][p][co]
    float* after = o2 + TOT;
    short* wcodes = (short*)after;               // 65536 shorts
    float* Wsum  = after + 32768;                // 256
    float* sc    = Wsum + 256;                   // 32
    unsigned* xsl   = (unsigned*)(sc + 32);      // 64
    unsigned* pwsl  = xsl + 64;                  // 2 (padded 64)
    unsigned* o2mnU = pwsl + 64;                 // 8192
    unsigned* o2mxU = o2mnU + 8192;              // 8192
    float* o2sm = (float*)(o2mxU + 8192);        // 8192
    float* h1mn = o2sm + 8192;                   // 8192
    float* h1mx = h1mn + 8192;                   // 8192
    float* h1sm = h1mx + 8192;                   // 8192
    float* P1 = h1sm + 8192; float* Q1 = P1 + 256;
    float* P2 = Q1 + 256;    float* Q2 = P2 + 256;

    k_init<<<32, 256, 0, stream>>>(xsl, pwsl, o2mnU, o2mxU, o2sm);
    k_pwmm<<<64, 256, 0, stream>>>((const float4*)pww, pwsl);
    k_minmax_x<<<dim3(16, 32), 256, 0, stream>>>((const float4*)x, xsl);
    k_fin1<<<1, 256, 0, stream>>>(dww, dwb, xsl, sc);
    k_dwconv<<<NB * NCH, 256, 0, stream>>>((const float4*)x, dww, dwb, h1, sc, h1mn, h1mx, h1sm);
    k_stats1<<<1, 256, 0, stream>>>(h1mn, h1mx, h1sm, bn1w, bn1b, pwsl, sc, P1, Q1);
    k_qw<<<256, 256, 0, stream>>>(pww, sc, wcodes, Wsum);
    k_gemm<<<dim3(49, 32), 256, 0, stream>>>(h1, wcodes, Wsum, sc, P1, Q1, o2, o2mnU, o2mxU, o2sm);
    k_stats2<<<1, 256, 0, stream>>>(o2mnU, o2mxU, o2sm, bn2w, bn2b, sc, P2, Q2);
    k_apply<<<dim3(49, 4, 32), 256, 0, stream>>>(o2, sc, P2, Q2, (float*)d_out);
}

// Round 5
// 385.323 us; speedup vs baseline: 2.3928x; 1.1420x over previous
//
#include <hip/hip_runtime.h>
#include <math.h>

#define IMG 56
#define HW 3136          // 56*56
#define NCH 256
#define NB 32
#define SAMPLE (NCH*HW)  // 802816
#define TOT (NB*SAMPLE)  // 25690112
#define ASTR 132         // As row stride in dwords (16B-aligned, bank-spread)

typedef short s16x8 __attribute__((ext_vector_type(8)));
typedef float f32x4 __attribute__((ext_vector_type(4)));

// ---------- helpers ----------

__device__ __forceinline__ float qz(float x, float mn, float scale) {
    float t = (x - mn) / scale;
    t = fminf(fmaxf(t, 0.f), 255.f);
    return rintf(t) * scale + mn;   // rintf = round-half-even, matches jnp.round
}

__device__ __forceinline__ float codef(float x, float mn, float scale) {
    return rintf(fminf(fmaxf((x - mn) / scale, 0.f), 255.f));   // integer code 0..255
}

// exact bf16 bits for small non-negative integers (mantissa fits, no rounding)
__device__ __forceinline__ unsigned bf16u(float v) {
    return (__float_as_uint(v) >> 16) & 0xFFFFu;
}

// order-preserving float<->uint encode for atomicMin/Max on floats
__device__ __forceinline__ unsigned enc(float f) {
    unsigned u = __float_as_uint(f);
    return (u & 0x80000000u) ? ~u : (u ^ 0x80000000u);
}
__device__ __forceinline__ float dec(unsigned u) {
    unsigned v = (u & 0x80000000u) ? (u ^ 0x80000000u) : ~u;
    return __uint_as_float(v);
}

// block-level min/max reduce (result valid on thread 0). blockDim must be mult of 64.
__device__ __forceinline__ void blk_red_minmax(float& mn, float& mx) {
    __shared__ float smn[4], smx[4];
    __syncthreads();
    #pragma unroll
    for (int o = 32; o > 0; o >>= 1) {
        mn = fminf(mn, __shfl_down(mn, o));
        mx = fmaxf(mx, __shfl_down(mx, o));
    }
    int lane = threadIdx.x & 63, w = threadIdx.x >> 6;
    if (lane == 0) { smn[w] = mn; smx[w] = mx; }
    __syncthreads();
    if (threadIdx.x == 0) {
        int nw = (int)blockDim.x >> 6;
        for (int i = 1; i < nw; i++) { mn = fminf(mn, smn[i]); mx = fmaxf(mx, smx[i]); }
    }
}

__device__ __forceinline__ void blk_red_minmax_bcast(float& mn, float& mx) {
    __shared__ float bb[2];
    blk_red_minmax(mn, mx);
    if (threadIdx.x == 0) { bb[0] = mn; bb[1] = mx; }
    __syncthreads();
    mn = bb[0]; mx = bb[1];
}

__device__ __forceinline__ float blk_red_sum(float v) {
    __shared__ float ss[4];
    __syncthreads();
    #pragma unroll
    for (int o = 32; o > 0; o >>= 1) v += __shfl_down(v, o);
    int lane = threadIdx.x & 63, w = threadIdx.x >> 6;
    if (lane == 0) ss[w] = v;
    __syncthreads();
    if (threadIdx.x == 0) {
        int nw = (int)blockDim.x >> 6;
        for (int i = 1; i < nw; i++) v += ss[i];
    }
    return v;
}

// ---------- kernels ----------

__global__ void k_init(unsigned* xsl, unsigned* pwsl, unsigned* o2mn, unsigned* o2mx, float* o2sum) {
    int i = blockIdx.x * 256 + threadIdx.x;   // grid 32 -> 8192
    o2mn[i] = 0xFFFFFFFFu; o2mx[i] = 0u; o2sum[i] = 0.f;
    if (blockIdx.x == 0) {
        if (threadIdx.x < 64) xsl[threadIdx.x] = (threadIdx.x < 32) ? 0xFFFFFFFFu : 0u;
        if (threadIdx.x == 64) { pwsl[0] = 0xFFFFFFFFu; pwsl[1] = 0u; }
    }
}

// pointwise-weight global min/max (65536 elems), 64 blocks
__global__ __launch_bounds__(256) void k_pwmm(const float4* __restrict__ pw4, unsigned* pwsl) {
    int i = blockIdx.x * 256 + threadIdx.x;
    float4 v = pw4[i];
    float mn = fminf(fminf(v.x, v.y), fminf(v.z, v.w));
    float mx = fmaxf(fmaxf(v.x, v.y), fmaxf(v.z, v.w));
    blk_red_minmax(mn, mx);
    if (threadIdx.x == 0) { atomicMin(&pwsl[0], enc(mn)); atomicMax(&pwsl[1], enc(mx)); }
}

// per-sample min/max of x. grid (16 chunks, 32 samples)
__global__ __launch_bounds__(256) void k_minmax_x(const float4* __restrict__ x4, unsigned* xsl) {
    int b = blockIdx.y, blk = blockIdx.x;
    const float4* p = x4 + (size_t)b * 200704 + (size_t)blk * 12544;
    float mn = INFINITY, mx = -INFINITY;
    for (int k = threadIdx.x; k < 12544; k += 256) {
        float4 v = p[k];
        mn = fminf(mn, fminf(fminf(v.x, v.y), fminf(v.z, v.w)));
        mx = fmaxf(mx, fmaxf(fmaxf(v.x, v.y), fmaxf(v.z, v.w)));
    }
    blk_red_minmax(mn, mx);
    if (threadIdx.x == 0) {
        atomicMin(&xsl[b], enc(mn));
        atomicMax(&xsl[32 + b], enc(mx));
    }
}

// sc layout: 0 mn_x 1 s_x | 2 mn_w1 3 s_w1 | 4 mn_b1 5 s_b1 | 6 mn_h1 7 s_h1
//            8 mn_h2 9 s_h2 | 10 mn_w2 11 s_w2 | 12 mn_o2 13 s_o2 | 14 r1=1/s1 15 B1=-mn1/s1
__global__ void k_fin1(const float* __restrict__ dww, const float* __restrict__ dwb,
                       const unsigned* __restrict__ xsl, float* sc) {
    int tid = threadIdx.x;
    float mn = INFINITY, mx = -INFINITY;
    for (int i = tid; i < 2304; i += 256) { float v = dww[i]; mn = fminf(mn, v); mx = fmaxf(mx, v); }
    blk_red_minmax(mn, mx);
    float w1min = mn, w1max = mx;
    float v = dwb[tid]; mn = v; mx = v;
    blk_red_minmax(mn, mx);
    if (tid == 0) {
        float sm = 0.f, sx = 0.f;
        for (int i = 0; i < 32; i++) { sm += dec(xsl[i]); sx += dec(xsl[32 + i]); }
        float m = sm / 32.f, X = sx / 32.f;
        sc[0] = m;      sc[1] = fmaxf((X - m) / 255.f, 1e-8f);
        sc[2] = w1min;  sc[3] = fmaxf((w1max - w1min) / 255.f, 1e-8f);
        sc[4] = mn;     sc[5] = fmaxf((mx - mn) / 255.f, 1e-8f);
    }
}

// depthwise 3x3 pad=1; float4 staged LDS tile (stride 68, left pad 4), float4 outputs
__global__ __launch_bounds__(256) void k_dwconv(const float4* __restrict__ x4, const float* __restrict__ w,
                                                const float* __restrict__ bias, float* __restrict__ h1,
                                                const float* __restrict__ sc,
                                                float* __restrict__ h1mn, float* __restrict__ h1mx,
                                                float* __restrict__ h1sm) {
    int bc = blockIdx.x, c = bc & 255;
    __shared__ float tile[58 * 68];
    int tid = threadIdx.x;
    for (int i = tid; i < 58 * 68; i += 256) tile[i] = 0.f;
    __syncthreads();
    float mnx = sc[0], scx = sc[1];
    const float4* px = x4 + (size_t)bc * 784;
    #pragma unroll
    for (int it = 0; it < 4; it++) {
        int idx = it * 256 + tid;
        if (idx < 784) {
            int i = idx / 14, j = (idx - i * 14) * 4;
            float4 v = px[idx];
            v.x = qz(v.x, mnx, scx); v.y = qz(v.y, mnx, scx);
            v.z = qz(v.z, mnx, scx); v.w = qz(v.w, mnx, scx);
            *(float4*)&tile[(i + 1) * 68 + j + 4] = v;
        }
    }
    __syncthreads();
    float qw[9];
    #pragma unroll
    for (int k = 0; k < 9; k++) qw[k] = qz(w[c * 9 + k], sc[2], sc[3]);
    float qb = qz(bias[c], sc[4], sc[5]);
    float4* po = (float4*)(h1 + (size_t)bc * HW);
    float lmn = INFINITY, lmx = -INFINITY, lsum = 0.f;
    #pragma unroll
    for (int it = 0; it < 4; it++) {
        int idx = it * 256 + tid;
        if (idx < 784) {
            int i = idx / 14, j = (idx - i * 14) * 4;
            float o0 = qb, o1 = qb, o2v = qb, o3 = qb;
            #pragma unroll
            for (int r = 0; r < 3; r++) {
                const float* row = &tile[(i + r) * 68 + j + 3];
                float a0 = row[0];
                float4 mid = *(const float4*)&row[1];
                float a5 = row[5];
                float w0 = qw[3 * r], w1 = qw[3 * r + 1], w2 = qw[3 * r + 2];
                o0  += a0    * w0 + mid.x * w1 + mid.y * w2;
                o1  += mid.x * w0 + mid.y * w1 + mid.z * w2;
                o2v += mid.y * w0 + mid.z * w1 + mid.w * w2;
                o3  += mid.z * w0 + mid.w * w1 + a5    * w2;
            }
            po[idx] = make_float4(o0, o1, o2v, o3);
            lmn = fminf(lmn, fminf(fminf(o0, o1), fminf(o2v, o3)));
            lmx = fmaxf(lmx, fmaxf(fmaxf(o0, o1), fmaxf(o2v, o3)));
            lsum += (o0 + o1) + (o2v + o3);
        }
    }
    blk_red_minmax(lmn, lmx);
    float ls = blk_red_sum(lsum);
    if (tid == 0) { h1mn[bc] = lmn; h1mx[bc] = lmx; h1sm[bc] = ls; }
}

// all h1-derived scalars/coeffs, wave-parallel. Outputs: sc[6..11,14,15], P1/Q1,
// and fused-quantize coeffs A2v[ci]=P1/s2, B2v[ci]=(Q1-mn2)/s2.
__global__ __launch_bounds__(256) void k_stats1(const float* __restrict__ h1mn, const float* __restrict__ h1mx,
                                                const float* __restrict__ h1sm,
                                                const float* __restrict__ bn1w, const float* __restrict__ bn1b,
                                                const unsigned* __restrict__ pwsl, float* sc,
                                                float* __restrict__ P1, float* __restrict__ Q1,
                                                float* __restrict__ A2v, float* __restrict__ B2v) {
    int tid = threadIdx.x, lane = tid & 63, w = tid >> 6;
    __shared__ float bmn[32], bmx[32], sp[4], lP[256], lQ[256];
    // phase 1: per-sample min/max over channels (wave w: b = 8w..8w+7)
    #pragma unroll
    for (int i = 0; i < 8; i++) {
        int b = w * 8 + i;
        float4 m4 = *(const float4*)&h1mn[b * 256 + lane * 4];
        float4 x4 = *(const float4*)&h1mx[b * 256 + lane * 4];
        float mn = fminf(fminf(m4.x, m4.y), fminf(m4.z, m4.w));
        float mx = fmaxf(fmaxf(x4.x, x4.y), fmaxf(x4.z, x4.w));
        #pragma unroll
        for (int o = 32; o > 0; o >>= 1) { mn = fminf(mn, __shfl_down(mn, o)); mx = fmaxf(mx, __shfl_down(mx, o)); }
        if (lane == 0) { bmn[b] = mn; bmx[b] = mx; }
    }
    __syncthreads();
    if (tid == 0) {
        float sm = 0.f, sx = 0.f;
        for (int i = 0; i < 32; i++) { sm += bmn[i]; sx += bmx[i]; }
        float m = sm / 32.f, X = sx / 32.f;
        sp[0] = m; sp[1] = fmaxf((X - m) / 255.f, 1e-8f);
        sc[6] = sp[0]; sc[7] = sp[1];
        sc[14] = 1.f / sp[1];
        sc[15] = -sp[0] / sp[1];
        float pmn = dec(pwsl[0]), pmx = dec(pwsl[1]);
        sc[10] = pmn; sc[11] = fmaxf((pmx - pmn) / 255.f, 1e-8f);
    }
    __syncthreads();
    float mn1 = sp[0], s1 = sp[1];
    // phase b: per-channel RangeBN (c = tid)
    int c = tid;
    float mmax = 0.f, mmin = 0.f, sum = 0.f;
    for (int ck = 0; ck < 16; ck++) {
        float c0n = h1mn[(2 * ck) * 256 + c], c1n = h1mn[(2 * ck + 1) * 256 + c];
        float c0x = h1mx[(2 * ck) * 256 + c], c1x = h1mx[(2 * ck + 1) * 256 + c];
        mmin += qz(fminf(c0n, c1n), mn1, s1);
        mmax += qz(fmaxf(c0x, c1x), mn1, s1);
        sum  += h1sm[(2 * ck) * 256 + c] + h1sm[(2 * ck + 1) * 256 + c];
    }
    mmin *= 0.0625f; mmax *= 0.0625f;
    float mean = sum / 100352.f;
    const float scale_fix = (float)(0.175 * (1.0 + sqrt(3.14159265358979323846 * log(4.0))) / sqrt(2.0 * log(6272.0)));
    float scale = 1.f / ((mmax - mmin) * scale_fix + 1e-5f);
    float ssn = scale, ssx = scale;
    blk_red_minmax_bcast(ssn, ssx);
    float wv = bn1w[c];
    float wmn = wv, wmx = wv;
    blk_red_minmax_bcast(wmn, wmx);
    float qs = qz(scale, ssn, fmaxf((ssx - ssn) / 255.f, 1e-8f));
    float qw = qz(wv, wmn, fmaxf((wmx - wmn) / 255.f, 1e-8f));
    float a1 = qs * qw;
    float be = bn1b[c] - mean * a1;
    float p1v = s1 * a1, q1v = mn1 * a1 + be;
    P1[c] = p1v; Q1[c] = q1v; lP[c] = p1v; lQ[c] = q1v;
    __syncthreads();
    // phase c: analytic h2 per-sample min/max (monotone chain)
    #pragma unroll
    for (int i = 0; i < 8; i++) {
        int b = w * 8 + i;
        float4 m4 = *(const float4*)&h1mn[b * 256 + lane * 4];
        float4 x4 = *(const float4*)&h1mx[b * 256 + lane * 4];
        float mn = INFINITY, mx = -INFINITY;
        #pragma unroll
        for (int j = 0; j < 4; j++) {
            int cc = lane * 4 + j;
            float kn = rintf(fminf(fmaxf(((&m4.x)[j] - mn1) / s1, 0.f), 255.f));
            float kx = rintf(fminf(fmaxf(((&x4.x)[j] - mn1) / s1, 0.f), 255.f));
            float hn = fmaxf(kn * lP[cc] + lQ[cc], 0.f);
            float hx = fmaxf(kx * lP[cc] + lQ[cc], 0.f);
            mn = fminf(mn, hn); mx = fmaxf(mx, hx);
        }
        #pragma unroll
        for (int o = 32; o > 0; o >>= 1) { mn = fminf(mn, __shfl_down(mn, o)); mx = fmaxf(mx, __shfl_down(mx, o)); }
        if (lane == 0) { bmn[b] = mn; bmx[b] = mx; }
    }
    __syncthreads();
    if (tid == 0) {
        float sm = 0.f, sx = 0.f;
        for (int i = 0; i < 32; i++) { sm += bmn[i]; sx += bmx[i]; }
        float m = sm / 32.f, X = sx / 32.f;
        sp[2] = m; sp[3] = fmaxf((X - m) / 255.f, 1e-8f);
        sc[8] = sp[2]; sc[9] = sp[3];
    }
    __syncthreads();
    A2v[c] = lP[c] / sp[3];
    B2v[c] = (lQ[c] - sp[2]) / sp[3];
}

// pw-weight integer codes (bf16 bits, layout [co][ci], K-contiguous) + per-co code sums
__global__ __launch_bounds__(256) void k_qw(const float* __restrict__ pw, const float* __restrict__ sc,
                                            short* __restrict__ wcodes, float* __restrict__ Wsum) {
    int co = blockIdx.x, ci = threadIdx.x;
    float kw = codef(pw[co * 256 + ci], sc[10], sc[11]);
    wcodes[co * 256 + ci] = (short)bf16u(kw);
    float s = blk_red_sum(kw);
    if (ci == 0) Wsum[co] = s;
}

// Fused convert+MFMA GEMM on integer codes (exact):
// phase A: thread owns p = p0+lane; wave w converts ci = 64w..64w+63 (coalesced row reads),
//          packs codes into AsU[p][d] (2 codes/dword, stride 132, single barrier).
// phase B: 8 k-steps x 16 MFMA, B-frags prefetched from global (L2-hot).
__global__ __launch_bounds__(256) void k_gemm(const float* __restrict__ h1, const short* __restrict__ wcodes,
                                              const float* __restrict__ Wsum, const float* __restrict__ sc,
                                              const float* __restrict__ A2v, const float* __restrict__ B2v,
                                              float* __restrict__ o2,
                                              unsigned* o2mn, unsigned* o2mx, float* o2sum) {
    int b = blockIdx.y, p0 = blockIdx.x * 64;
    __shared__ unsigned AsU[64 * ASTR];
    __shared__ float BpW[4][64];
    __shared__ float BpT[64];
    int tid = threadIdx.x, lane = tid & 63, w = tid >> 6;
    int col = lane & 15, quad = lane >> 4;
    float A1 = sc[14], B1 = sc[15];
    const float* colp = h1 + (size_t)b * SAMPLE + p0 + lane;
    unsigned base = lane * ASTR + 32 * w;
    float bp = 0.f;
    for (int t2 = 0; t2 < 16; t2++) {
        int d0 = 2 * t2;
        int ci = 64 * w + 2 * d0;
        float v0 = colp[(size_t)ci * HW];
        float v1 = colp[(size_t)(ci + 1) * HW];
        float v2 = colp[(size_t)(ci + 2) * HW];
        float v3 = colp[(size_t)(ci + 3) * HW];
        float k0f = rintf(fminf(fmaxf(fmaf(v0, A1, B1), 0.f), 255.f));
        float k1f = rintf(fminf(fmaxf(fmaf(v1, A1, B1), 0.f), 255.f));
        float k2f = rintf(fminf(fmaxf(fmaf(v2, A1, B1), 0.f), 255.f));
        float k3f = rintf(fminf(fmaxf(fmaf(v3, A1, B1), 0.f), 255.f));
        float c0 = rintf(fminf(fmaxf(fmaf(k0f, A2v[ci],     B2v[ci]),     0.f), 255.f));
        float c1 = rintf(fminf(fmaxf(fmaf(k1f, A2v[ci + 1], B2v[ci + 1]), 0.f), 255.f));
        float c2 = rintf(fminf(fmaxf(fmaf(k2f, A2v[ci + 2], B2v[ci + 2]), 0.f), 255.f));
        float c3 = rintf(fminf(fmaxf(fmaf(k3f, A2v[ci + 3], B2v[ci + 3]), 0.f), 255.f));
        bp += (c0 + c1) + (c2 + c3);
        uint2 pk;
        pk.x = bf16u(c0) | (bf16u(c1) << 16);
        pk.y = bf16u(c2) | (bf16u(c3) << 16);
        *(uint2*)&AsU[base + d0] = pk;
    }
    BpW[w][lane] = bp;
    __syncthreads();
    const short* wb = wcodes + (size_t)(w * 64 + col) * 256 + quad * 8;
    f32x4 acc[4][4];
    #pragma unroll
    for (int i = 0; i < 4; i++)
        #pragma unroll
        for (int j = 0; j < 4; j++) acc[i][j] = (f32x4){0.f, 0.f, 0.f, 0.f};
    s16x8 bcur[4];
    #pragma unroll
    for (int nt = 0; nt < 4; nt++) bcur[nt] = *(const s16x8*)(wb + (size_t)nt * 4096);
    for (int step = 0; step < 8; step++) {
        s16x8 af[4];
        #pragma unroll
        for (int mt = 0; mt < 4; mt++)
            af[mt] = *(const s16x8*)&AsU[(size_t)(mt * 16 + col) * ASTR + step * 16 + quad * 4];
        s16x8 bnx[4];
        if (step < 7) {
            #pragma unroll
            for (int nt = 0; nt < 4; nt++) bnx[nt] = *(const s16x8*)(wb + (size_t)nt * 4096 + (step + 1) * 32);
        }
        #pragma unroll
        for (int mt = 0; mt < 4; mt++)
            #pragma unroll
            for (int nt = 0; nt < 4; nt++)
                acc[mt][nt] = __builtin_amdgcn_mfma_f32_16x16x32_bf16(af[mt], bcur[nt], acc[mt][nt], 0, 0, 0);
        if (step < 7) {
            #pragma unroll
            for (int nt = 0; nt < 4; nt++) bcur[nt] = bnx[nt];
        }
    }
    if (tid < 64) BpT[tid] = BpW[0][tid] + BpW[1][tid] + BpW[2][tid] + BpW[3][tid];
    __syncthreads();
    float alpha = sc[11] * sc[9];            // sw*s2   (D coeff)
    float beta  = sc[11] * sc[8];            // sw*mn2  (W[co] coeff)
    float gamma = sc[10] * sc[9];            // mnw*s2  (Bp coeff)
    float delta = 256.f * sc[10] * sc[8];    // 256*mnw*mn2
    float Wv[4];
    #pragma unroll
    for (int nt = 0; nt < 4; nt++) Wv[nt] = Wsum[w * 64 + nt * 16 + col];
    float snn[4], sxx[4], ssm[4];
    #pragma unroll
    for (int nt = 0; nt < 4; nt++) { snn[nt] = INFINITY; sxx[nt] = -INFINITY; ssm[nt] = 0.f; }
    float* obase = o2 + ((size_t)b * HW + p0) * 256 + w * 64 + col;
    #pragma unroll
    for (int mt = 0; mt < 4; mt++) {
        float bp4[4];
        #pragma unroll
        for (int r = 0; r < 4; r++) bp4[r] = BpT[mt * 16 + quad * 4 + r];
        #pragma unroll
        for (int nt = 0; nt < 4; nt++) {
            float wterm = beta * Wv[nt] + delta;
            #pragma unroll
            for (int r = 0; r < 4; r++) {
                float val = alpha * acc[mt][nt][r] + gamma * bp4[r] + wterm;
                obase[(size_t)(mt * 16 + quad * 4 + r) * 256 + nt * 16] = val;
                snn[nt] = fminf(snn[nt], val);
                sxx[nt] = fmaxf(sxx[nt], val);
                ssm[nt] += val;
            }
        }
    }
    #pragma unroll
    for (int nt = 0; nt < 4; nt++) {
        snn[nt] = fminf(snn[nt], __shfl_xor(snn[nt], 16));
        sxx[nt] = fmaxf(sxx[nt], __shfl_xor(sxx[nt], 16));
        ssm[nt] += __shfl_xor(ssm[nt], 16);
        snn[nt] = fminf(snn[nt], __shfl_xor(snn[nt], 32));
        sxx[nt] = fmaxf(sxx[nt], __shfl_xor(sxx[nt], 32));
        ssm[nt] += __shfl_xor(ssm[nt], 32);
    }
    if (lane < 16) {
        #pragma unroll
        for (int nt = 0; nt < 4; nt++) {
            int idx = b * 256 + w * 64 + nt * 16 + lane;
            atomicMin(&o2mn[idx], enc(snn[nt]));
            atomicMax(&o2mx[idx], enc(sxx[nt]));
            atomicAdd(&o2sum[idx], ssm[nt]);
        }
    }
}

// out2-derived scalars/coeffs, wave-parallel phase 1.
__global__ __launch_bounds__(256) void k_stats2(const unsigned* __restrict__ o2mnU, const unsigned* __restrict__ o2mxU,
                                                const float* __restrict__ o2sm,
                                                const float* __restrict__ bn2w, const float* __restrict__ bn2b,
                                                float* sc, float* __restrict__ P2, float* __restrict__ Q2) {
    int tid = threadIdx.x, lane = tid & 63, w = tid >> 6;
    __shared__ float bmn[32], bmx[32], sp[2];
    #pragma unroll
    for (int i = 0; i < 8; i++) {
        int b = w * 8 + i;
        uint4 um = *(const uint4*)&o2mnU[b * 256 + lane * 4];
        uint4 ux = *(const uint4*)&o2mxU[b * 256 + lane * 4];
        float mn = fminf(fminf(dec(um.x), dec(um.y)), fminf(dec(um.z), dec(um.w)));
        float mx = fmaxf(fmaxf(dec(ux.x), dec(ux.y)), fmaxf(dec(ux.z), dec(ux.w)));
        #pragma unroll
        for (int o = 32; o > 0; o >>= 1) { mn = fminf(mn, __shfl_down(mn, o)); mx = fmaxf(mx, __shfl_down(mx, o)); }
        if (lane == 0) { bmn[b] = mn; bmx[b] = mx; }
    }
    __syncthreads();
    if (tid == 0) {
        float sm = 0.f, sx = 0.f;
        for (int i = 0; i < 32; i++) { sm += bmn[i]; sx += bmx[i]; }
        float m = sm / 32.f, X = sx / 32.f;
        sp[0] = m; sp[1] = fmaxf((X - m) / 255.f, 1e-8f);
        sc[12] = sp[0]; sc[13] = sp[1];
    }
    __syncthreads();
    float mno = sp[0], so = sp[1];
    int c = tid;
    float mmax = 0.f, mmin = 0.f, sum = 0.f;
    for (int ck = 0; ck < 16; ck++) {
        float c0n = dec(o2mnU[(2 * ck) * 256 + c]), c1n = dec(o2mnU[(2 * ck + 1) * 256 + c]);
        float c0x = dec(o2mxU[(2 * ck) * 256 + c]), c1x = dec(o2mxU[(2 * ck + 1) * 256 + c]);
        mmin += qz(fminf(c0n, c1n), mno, so);
        mmax += qz(fmaxf(c0x, c1x), mno, so);
        sum  += o2sm[(2 * ck) * 256 + c] + o2sm[(2 * ck + 1) * 256 + c];
    }
    mmin *= 0.0625f; mmax *= 0.0625f;
    float mean = sum / 100352.f;
    const float scale_fix = (float)(0.175 * (1.0 + sqrt(3.14159265358979323846 * log(4.0))) / sqrt(2.0 * log(6272.0)));
    float scale = 1.f / ((mmax - mmin) * scale_fix + 1e-5f);
    float ssn = scale, ssx = scale;
    blk_red_minmax_bcast(ssn, ssx);
    float wv = bn2w[c];
    float wmn = wv, wmx = wv;
    blk_red_minmax_bcast(wmn, wmx);
    float qs = qz(scale, ssn, fmaxf((ssx - ssn) / 255.f, 1e-8f));
    float qw = qz(wv, wmn, fmaxf((wmx - wmn) / 255.f, 1e-8f));
    float a2 = qs * qw;
    float be = bn2b[c] - mean * a2;
    P2[c] = so * a2; Q2[c] = mno * a2 + be;
}

// final: transpose [b][p][co] -> NCHW [b][co][p] via LDS tile, map applied on write side
__global__ __launch_bounds__(256) void k_apply(const float* __restrict__ o2, const float* __restrict__ sc,
                                               const float* __restrict__ P2, const float* __restrict__ Q2,
                                               float* __restrict__ out) {
    __shared__ float tile[64][65];
    int b = blockIdx.z, p0 = blockIdx.x * 64, co0 = blockIdx.y * 64;
    int t = threadIdx.x, rr = t >> 4, cq = t & 15;
    float mno = sc[12], so = sc[13];
    #pragma unroll
    for (int it = 0; it < 4; it++) {
        int p = rr + 16 * it;
        float4 v = *(const float4*)&o2[((size_t)b * HW + p0 + p) * 256 + co0 + cq * 4];
        *(float4*)&tile[p][cq * 4] = v;
    }
    __syncthreads();
    #pragma unroll
    for (int it = 0; it < 4; it++) {
        int col = rr + 16 * it;             // local co
        int c = co0 + col;
        float pv = P2[c], qv = Q2[c];
        float4 r;
        #pragma unroll
        for (int j = 0; j < 4; j++) {
            float val = tile[cq * 4 + j][col];
            (&r.x)[j] = fmaxf(rintf(fminf(fmaxf((val - mno) / so, 0.f), 255.f)) * pv + qv, 0.f);
        }
        *(float4*)&out[((size_t)b * 256 + c) * HW + p0 + cq * 4] = r;
    }
}

// ---------- launch ----------

extern "C" void kernel_launch(void* const* d_in, const int* in_sizes, int n_in,
                              void* d_out, int out_size, void* d_ws, size_t ws_size,
                              hipStream_t stream) {
    (void)in_sizes; (void)n_in; (void)out_size; (void)ws_size;
    const float* x    = (const float*)d_in[0];
    const float* dww  = (const float*)d_in[1];
    const float* dwb  = (const float*)d_in[2];
    const float* bn1w = (const float*)d_in[3];
    const float* bn1b = (const float*)d_in[4];
    const float* pww  = (const float*)d_in[5];
    const float* bn2w = (const float*)d_in[6];
    const float* bn2b = (const float*)d_in[7];

    float* h1   = (float*)d_ws;                  // TOT  [b][ci][p]
    float* o2   = h1 + TOT;                      // TOT  [b][p][co]
    float* after = o2 + TOT;
    short* wcodes = (short*)after;               // 65536 shorts
    float* Wsum  = after + 32768;                // 256
    float* sc    = Wsum + 256;                   // 32
    unsigned* xsl   = (unsigned*)(sc + 32);      // 64
    unsigned* pwsl  = xsl + 64;                  // 2 (padded 64)
    unsigned* o2mnU = pwsl + 64;                 // 8192
    unsigned* o2mxU = o2mnU + 8192;              // 8192
    float* o2sm = (float*)(o2mxU + 8192);        // 8192
    float* h1mn = o2sm + 8192;                   // 8192
    float* h1mx = h1mn + 8192;                   // 8192
    float* h1sm = h1mx + 8192;                   // 8192
    float* P1 = h1sm + 8192; float* Q1 = P1 + 256;
    float* P2 = Q1 + 256;    float* Q2 = P2 + 256;
    float* A2v = Q2 + 256;   float* B2v = A2v + 256;

    k_init<<<32, 256, 0, stream>>>(xsl, pwsl, o2mnU, o2mxU, o2sm);
    k_pwmm<<<64, 256, 0, stream>>>((const float4*)pww, pwsl);
    k_minmax_x<<<dim3(16, 32), 256, 0, stream>>>((const float4*)x, xsl);
    k_fin1<<<1, 256, 0, stream>>>(dww, dwb, xsl, sc);
    k_dwconv<<<NB * NCH, 256, 0, stream>>>((const float4*)x, dww, dwb, h1, sc, h1mn, h1mx, h1sm);
    k_stats1<<<1, 256, 0, stream>>>(h1mn, h1mx, h1sm, bn1w, bn1b, pwsl, sc, P1, Q1, A2v, B2v);
    k_qw<<<256, 256, 0, stream>>>(pww, sc, wcodes, Wsum);
    k_gemm<<<dim3(49, 32), 256, 0, stream>>>(h1, wcodes, Wsum, sc, A2v, B2v, o2, o2mnU, o2mxU, o2sm);
    k_stats2<<<1, 256, 0, stream>>>(o2mnU, o2mxU, o2sm, bn2w, bn2b, sc, P2, Q2);
    k_apply<<<dim3(49, 4, 32), 256, 0, stream>>>(o2, sc, P2, Q2, (float*)d_out);
}

// Round 6
// 358.718 us; speedup vs baseline: 2.5702x; 1.0742x over previous
//
#include <hip/hip_runtime.h>
#include <math.h>

#define IMG 56
#define HW 3136          // 56*56
#define NCH 256
#define NB 32
#define SAMPLE (NCH*HW)  // 802816
#define TOT (NB*SAMPLE)  // 25690112
#define ASTR 68          // As row stride in dwords (16B-aligned, granule-uniform)

typedef int i32x4 __attribute__((ext_vector_type(4)));

// ---------- helpers ----------

__device__ __forceinline__ float qz(float x, float mn, float scale) {
    float t = (x - mn) / scale;
    t = fminf(fmaxf(t, 0.f), 255.f);
    return rintf(t) * scale + mn;   // rintf = round-half-even, matches jnp.round
}

__device__ __forceinline__ float codef(float x, float mn, float scale) {
    return rintf(fminf(fmaxf((x - mn) / scale, 0.f), 255.f));   // integer code 0..255
}

// order-preserving float<->uint encode for atomicMin/Max on floats
__device__ __forceinline__ unsigned enc(float f) {
    unsigned u = __float_as_uint(f);
    return (u & 0x80000000u) ? ~u : (u ^ 0x80000000u);
}
__device__ __forceinline__ float dec(unsigned u) {
    unsigned v = (u & 0x80000000u) ? (u ^ 0x80000000u) : ~u;
    return __uint_as_float(v);
}

// block-level min/max reduce (result valid on thread 0). blockDim must be mult of 64.
__device__ __forceinline__ void blk_red_minmax(float& mn, float& mx) {
    __shared__ float smn[4], smx[4];
    __syncthreads();
    #pragma unroll
    for (int o = 32; o > 0; o >>= 1) {
        mn = fminf(mn, __shfl_down(mn, o));
        mx = fmaxf(mx, __shfl_down(mx, o));
    }
    int lane = threadIdx.x & 63, w = threadIdx.x >> 6;
    if (lane == 0) { smn[w] = mn; smx[w] = mx; }
    __syncthreads();
    if (threadIdx.x == 0) {
        int nw = (int)blockDim.x >> 6;
        for (int i = 1; i < nw; i++) { mn = fminf(mn, smn[i]); mx = fmaxf(mx, smx[i]); }
    }
}

__device__ __forceinline__ void blk_red_minmax_bcast(float& mn, float& mx) {
    __shared__ float bb[2];
    blk_red_minmax(mn, mx);
    if (threadIdx.x == 0) { bb[0] = mn; bb[1] = mx; }
    __syncthreads();
    mn = bb[0]; mx = bb[1];
}

__device__ __forceinline__ float blk_red_sum(float v) {
    __shared__ float ss[4];
    __syncthreads();
    #pragma unroll
    for (int o = 32; o > 0; o >>= 1) v += __shfl_down(v, o);
    int lane = threadIdx.x & 63, w = threadIdx.x >> 6;
    if (lane == 0) ss[w] = v;
    __syncthreads();
    if (threadIdx.x == 0) {
        int nw = (int)blockDim.x >> 6;
        for (int i = 1; i < nw; i++) v += ss[i];
    }
    return v;
}

// ---------- kernels ----------

__global__ void k_init(unsigned* xsl, unsigned* pwsl, unsigned* o2mn, unsigned* o2mx, float* o2sum) {
    int i = blockIdx.x * 256 + threadIdx.x;   // grid 32 -> 8192
    o2mn[i] = 0xFFFFFFFFu; o2mx[i] = 0u; o2sum[i] = 0.f;
    if (blockIdx.x == 0) {
        if (threadIdx.x < 64) xsl[threadIdx.x] = (threadIdx.x < 32) ? 0xFFFFFFFFu : 0u;
        if (threadIdx.x == 64) { pwsl[0] = 0xFFFFFFFFu; pwsl[1] = 0u; }
    }
}

// merged front: blocks 0..511 per-sample min/max of x; blocks 512..575 pw min/max
__global__ __launch_bounds__(256) void k_front(const float4* __restrict__ x4, const float4* __restrict__ pw4,
                                               unsigned* xsl, unsigned* pwsl) {
    int id = blockIdx.x;
    if (id < 512) {
        int b = id >> 4, blk = id & 15;
        const float4* p = x4 + (size_t)b * 200704 + (size_t)blk * 12544;
        float mn = INFINITY, mx = -INFINITY;
        for (int k = threadIdx.x; k < 12544; k += 256) {
            float4 v = p[k];
            mn = fminf(mn, fminf(fminf(v.x, v.y), fminf(v.z, v.w)));
            mx = fmaxf(mx, fmaxf(fmaxf(v.x, v.y), fmaxf(v.z, v.w)));
        }
        blk_red_minmax(mn, mx);
        if (threadIdx.x == 0) {
            atomicMin(&xsl[b], enc(mn));
            atomicMax(&xsl[32 + b], enc(mx));
        }
    } else {
        int i = (id - 512) * 256 + threadIdx.x;
        float4 v = pw4[i];
        float mn = fminf(fminf(v.x, v.y), fminf(v.z, v.w));
        float mx = fmaxf(fmaxf(v.x, v.y), fmaxf(v.z, v.w));
        blk_red_minmax(mn, mx);
        if (threadIdx.x == 0) { atomicMin(&pwsl[0], enc(mn)); atomicMax(&pwsl[1], enc(mx)); }
    }
}

// sc layout: 0 mn_x 1 s_x | 2 mn_w1 3 s_w1 | 4 mn_b1 5 s_b1 | 6 mn_h1 7 s_h1
//            8 mn_h2 9 s_h2 | 10 mn_w2 11 s_w2 | 12 mn_o2 13 s_o2 | 14 r1=1/s1 15 B1=-mn1/s1
__global__ void k_fin1(const float* __restrict__ dww, const float* __restrict__ dwb,
                       const unsigned* __restrict__ xsl, const unsigned* __restrict__ pwsl, float* sc) {
    int tid = threadIdx.x;
    float mn = INFINITY, mx = -INFINITY;
    #pragma unroll
    for (int i = 0; i < 9; i++) {
        int idx = i * 256 + tid;
        if (idx < 2304) { float v = dww[idx]; mn = fminf(mn, v); mx = fmaxf(mx, v); }
    }
    blk_red_minmax(mn, mx);
    float w1min = mn, w1max = mx;
    float v = dwb[tid]; mn = v; mx = v;
    blk_red_minmax(mn, mx);
    if (tid == 0) {
        float sm = 0.f, sx = 0.f;
        for (int i = 0; i < 32; i++) { sm += dec(xsl[i]); sx += dec(xsl[32 + i]); }
        float m = sm / 32.f, X = sx / 32.f;
        sc[0] = m;      sc[1] = fmaxf((X - m) / 255.f, 1e-8f);
        sc[2] = w1min;  sc[3] = fmaxf((w1max - w1min) / 255.f, 1e-8f);
        sc[4] = mn;     sc[5] = fmaxf((mx - mn) / 255.f, 1e-8f);
        float pmn = dec(pwsl[0]), pmx = dec(pwsl[1]);
        sc[10] = pmn; sc[11] = fmaxf((pmx - pmn) / 255.f, 1e-8f);
    }
}

// pw-weight offset codes (i8 = code-128, layout [co][ci]) + per-co raw code sums
__global__ __launch_bounds__(256) void k_qw(const float* __restrict__ pw, const float* __restrict__ sc,
                                            char* __restrict__ wcodes, float* __restrict__ Wsum) {
    int co = blockIdx.x, ci = threadIdx.x;
    float kw = codef(pw[co * 256 + ci], sc[10], sc[11]);
    wcodes[co * 256 + ci] = (char)((int)kw - 128);
    float s = blk_red_sum(kw);
    if (ci == 0) Wsum[co] = s;
}

// depthwise 3x3 pad=1; float4 staged LDS tile (stride 68, left pad 4), halo-only zeroing
__global__ __launch_bounds__(256) void k_dwconv(const float4* __restrict__ x4, const float* __restrict__ w,
                                                const float* __restrict__ bias, float* __restrict__ h1,
                                                const float* __restrict__ sc,
                                                float* __restrict__ h1mn, float* __restrict__ h1mx,
                                                float* __restrict__ h1sm) {
    int bc = blockIdx.x, c = bc & 255;
    __shared__ float tile[58 * 68];
    int tid = threadIdx.x;
    // zero only the halo ring: rows 0,57 cols 3..60; cols 3,60 rows 1..56 (228 cells)
    if (tid < 228) {
        int row, col2;
        if (tid < 58)       { row = 0;              col2 = 3 + tid; }
        else if (tid < 116) { row = 57;             col2 = 3 + tid - 58; }
        else if (tid < 172) { row = 1 + tid - 116;  col2 = 3; }
        else                { row = 1 + tid - 172;  col2 = 60; }
        tile[row * 68 + col2] = 0.f;
    }
    float mnx = sc[0], scx = sc[1];
    const float4* px = x4 + (size_t)bc * 784;
    #pragma unroll
    for (int it = 0; it < 4; it++) {
        int idx = it * 256 + tid;
        if (idx < 784) {
            int i = idx / 14, j = (idx - i * 14) * 4;
            float4 v = px[idx];
            v.x = qz(v.x, mnx, scx); v.y = qz(v.y, mnx, scx);
            v.z = qz(v.z, mnx, scx); v.w = qz(v.w, mnx, scx);
            *(float4*)&tile[(i + 1) * 68 + j + 4] = v;
        }
    }
    __syncthreads();
    float qw[9];
    #pragma unroll
    for (int k = 0; k < 9; k++) qw[k] = qz(w[c * 9 + k], sc[2], sc[3]);
    float qb = qz(bias[c], sc[4], sc[5]);
    float4* po = (float4*)(h1 + (size_t)bc * HW);
    float lmn = INFINITY, lmx = -INFINITY, lsum = 0.f;
    #pragma unroll
    for (int it = 0; it < 4; it++) {
        int idx = it * 256 + tid;
        if (idx < 784) {
            int i = idx / 14, j = (idx - i * 14) * 4;
            float o0 = qb, o1 = qb, o2v = qb, o3 = qb;
            #pragma unroll
            for (int r = 0; r < 3; r++) {
                const float* row = &tile[(i + r) * 68 + j + 3];
                float a0 = row[0];
                float4 mid = *(const float4*)&row[1];
                float a5 = row[5];
                float w0 = qw[3 * r], w1 = qw[3 * r + 1], w2 = qw[3 * r + 2];
                o0  += a0    * w0 + mid.x * w1 + mid.y * w2;
                o1  += mid.x * w0 + mid.y * w1 + mid.z * w2;
                o2v += mid.y * w0 + mid.z * w1 + mid.w * w2;
                o3  += mid.z * w0 + mid.w * w1 + a5    * w2;
            }
            po[idx] = make_float4(o0, o1, o2v, o3);
            lmn = fminf(lmn, fminf(fminf(o0, o1), fminf(o2v, o3)));
            lmx = fmaxf(lmx, fmaxf(fmaxf(o0, o1), fmaxf(o2v, o3)));
            lsum += (o0 + o1) + (o2v + o3);
        }
    }
    blk_red_minmax(lmn, lmx);
    float ls = blk_red_sum(lsum);
    if (tid == 0) { h1mn[bc] = lmn; h1mx[bc] = lmx; h1sm[bc] = ls; }
}

// all h1-derived scalars/coeffs, wave-parallel. Outputs sc[6..9,14,15], A2v/B2v.
__global__ __launch_bounds__(256) void k_stats1(const float* __restrict__ h1mn, const float* __restrict__ h1mx,
                                                const float* __restrict__ h1sm,
                                                const float* __restrict__ bn1w, const float* __restrict__ bn1b,
                                                float* sc,
                                                float* __restrict__ A2v, float* __restrict__ B2v) {
    int tid = threadIdx.x, lane = tid & 63, w = tid >> 6;
    __shared__ float bmn[32], bmx[32], sp[4], lP[256], lQ[256];
    // phase 1: per-sample min/max over channels (wave w: b = 8w..8w+7)
    #pragma unroll
    for (int i = 0; i < 8; i++) {
        int b = w * 8 + i;
        float4 m4 = *(const float4*)&h1mn[b * 256 + lane * 4];
        float4 x4 = *(const float4*)&h1mx[b * 256 + lane * 4];
        float mn = fminf(fminf(m4.x, m4.y), fminf(m4.z, m4.w));
        float mx = fmaxf(fmaxf(x4.x, x4.y), fmaxf(x4.z, x4.w));
        #pragma unroll
        for (int o = 32; o > 0; o >>= 1) { mn = fminf(mn, __shfl_down(mn, o)); mx = fmaxf(mx, __shfl_down(mx, o)); }
        if (lane == 0) { bmn[b] = mn; bmx[b] = mx; }
    }
    __syncthreads();
    if (tid == 0) {
        float sm = 0.f, sx = 0.f;
        for (int i = 0; i < 32; i++) { sm += bmn[i]; sx += bmx[i]; }
        float m = sm / 32.f, X = sx / 32.f;
        sp[0] = m; sp[1] = fmaxf((X - m) / 255.f, 1e-8f);
        sc[6] = sp[0]; sc[7] = sp[1];
        sc[14] = 1.f / sp[1];
        sc[15] = -sp[0] / sp[1];
    }
    __syncthreads();
    float mn1 = sp[0], s1 = sp[1];
    // phase b: per-channel RangeBN (c = tid), fully unrolled loads
    int c = tid;
    float mmax = 0.f, mmin = 0.f, sum = 0.f;
    #pragma unroll
    for (int ck = 0; ck < 16; ck++) {
        float c0n = h1mn[(2 * ck) * 256 + c], c1n = h1mn[(2 * ck + 1) * 256 + c];
        float c0x = h1mx[(2 * ck) * 256 + c], c1x = h1mx[(2 * ck + 1) * 256 + c];
        mmin += qz(fminf(c0n, c1n), mn1, s1);
        mmax += qz(fmaxf(c0x, c1x), mn1, s1);
        sum  += h1sm[(2 * ck) * 256 + c] + h1sm[(2 * ck + 1) * 256 + c];
    }
    mmin *= 0.0625f; mmax *= 0.0625f;
    float mean = sum / 100352.f;
    const float scale_fix = (float)(0.175 * (1.0 + sqrt(3.14159265358979323846 * log(4.0))) / sqrt(2.0 * log(6272.0)));
    float scale = 1.f / ((mmax - mmin) * scale_fix + 1e-5f);
    float ssn = scale, ssx = scale;
    blk_red_minmax_bcast(ssn, ssx);
    float wv = bn1w[c];
    float wmn = wv, wmx = wv;
    blk_red_minmax_bcast(wmn, wmx);
    float qs = qz(scale, ssn, fmaxf((ssx - ssn) / 255.f, 1e-8f));
    float qw = qz(wv, wmn, fmaxf((wmx - wmn) / 255.f, 1e-8f));
    float a1 = qs * qw;
    float be = bn1b[c] - mean * a1;
    float p1v = s1 * a1, q1v = mn1 * a1 + be;
    lP[c] = p1v; lQ[c] = q1v;
    __syncthreads();
    // phase c: analytic h2 per-sample min/max (monotone chain)
    #pragma unroll
    for (int i = 0; i < 8; i++) {
        int b = w * 8 + i;
        float4 m4 = *(const float4*)&h1mn[b * 256 + lane * 4];
        float4 x4 = *(const float4*)&h1mx[b * 256 + lane * 4];
        float mn = INFINITY, mx = -INFINITY;
        #pragma unroll
        for (int j = 0; j < 4; j++) {
            int cc = lane * 4 + j;
            float kn = rintf(fminf(fmaxf(((&m4.x)[j] - mn1) / s1, 0.f), 255.f));
            float kx = rintf(fminf(fmaxf(((&x4.x)[j] - mn1) / s1, 0.f), 255.f));
            float hn = fmaxf(kn * lP[cc] + lQ[cc], 0.f);
            float hx = fmaxf(kx * lP[cc] + lQ[cc], 0.f);
            mn = fminf(mn, hn); mx = fmaxf(mx, hx);
        }
        #pragma unroll
        for (int o = 32; o > 0; o >>= 1) { mn = fminf(mn, __shfl_down(mn, o)); mx = fmaxf(mx, __shfl_down(mx, o)); }
        if (lane == 0) { bmn[b] = mn; bmx[b] = mx; }
    }
    __syncthreads();
    if (tid == 0) {
        float sm = 0.f, sx = 0.f;
        for (int i = 0; i < 32; i++) { sm += bmn[i]; sx += bmx[i]; }
        float m = sm / 32.f, X = sx / 32.f;
        sp[2] = m; sp[3] = fmaxf((X - m) / 255.f, 1e-8f);
        sc[8] = sp[2]; sc[9] = sp[3];
    }
    __syncthreads();
    A2v[c] = lP[c] / sp[3];
    B2v[c] = (lQ[c] - sp[2]) / sp[3];
}

// Fused convert + i8-MFMA GEMM on offset integer codes (exact):
// D'[p,co] = sum_ci (kh-128)(kw-128); D = D' + 128*(Wsum+Bp) - 4194304.
// phase A: thread owns p = p0+lane; wave w converts ci = 64w..64w+63 (coalesced),
//          packs 4 offset codes/dword into AsU (stride 68), single barrier.
// phase B: 4 k-steps x 16 MFMA (K=64), B-frags prefetched from global (L2-hot).
__global__ __launch_bounds__(256) void k_gemm(const float* __restrict__ h1, const char* __restrict__ wcodes,
                                              const float* __restrict__ Wsum, const float* __restrict__ sc,
                                              const float* __restrict__ A2v, const float* __restrict__ B2v,
                                              float* __restrict__ o2,
                                              unsigned* o2mn, unsigned* o2mx, float* o2sum) {
    int b = blockIdx.y, p0 = blockIdx.x * 64;
    __shared__ unsigned AsU[64 * ASTR];    // 17.4 KB: [p][16 dwords per wave-chunk]
    __shared__ float BpW[4][64];
    __shared__ float BpT[64];
    int tid = threadIdx.x, lane = tid & 63, w = tid >> 6;
    int col = lane & 15, quad = lane >> 4;
    float A1 = sc[14], B1 = sc[15];
    const float* colp = h1 + (size_t)b * SAMPLE + p0 + lane;
    unsigned base = lane * ASTR + 16 * w;
    float bp = 0.f;
    #pragma unroll 4
    for (int t2 = 0; t2 < 16; t2++) {
        int ci = 64 * w + 4 * t2;
        float v0 = colp[(size_t)ci * HW];
        float v1 = colp[(size_t)(ci + 1) * HW];
        float v2 = colp[(size_t)(ci + 2) * HW];
        float v3 = colp[(size_t)(ci + 3) * HW];
        float k0f = rintf(fminf(fmaxf(fmaf(v0, A1, B1), 0.f), 255.f));
        float k1f = rintf(fminf(fmaxf(fmaf(v1, A1, B1), 0.f), 255.f));
        float k2f = rintf(fminf(fmaxf(fmaf(v2, A1, B1), 0.f), 255.f));
        float k3f = rintf(fminf(fmaxf(fmaf(v3, A1, B1), 0.f), 255.f));
        float c0 = rintf(fminf(fmaxf(fmaf(k0f, A2v[ci],     B2v[ci]),     0.f), 255.f));
        float c1 = rintf(fminf(fmaxf(fmaf(k1f, A2v[ci + 1], B2v[ci + 1]), 0.f), 255.f));
        float c2 = rintf(fminf(fmaxf(fmaf(k2f, A2v[ci + 2], B2v[ci + 2]), 0.f), 255.f));
        float c3 = rintf(fminf(fmaxf(fmaf(k3f, A2v[ci + 3], B2v[ci + 3]), 0.f), 255.f));
        bp += (c0 + c1) + (c2 + c3);
        unsigned b0 = (unsigned)(((int)c0 - 128) & 0xFF);
        unsigned b1 = (unsigned)(((int)c1 - 128) & 0xFF);
        unsigned b2 = (unsigned)(((int)c2 - 128) & 0xFF);
        unsigned b3 = (unsigned)(((int)c3 - 128) & 0xFF);
        AsU[base + t2] = b0 | (b1 << 8) | (b2 << 16) | (b3 << 24);
    }
    BpW[w][lane] = bp;
    __syncthreads();
    const char* wb = wcodes + (size_t)(w * 64 + col) * 256 + quad * 16;
    i32x4 acc[4][4];
    #pragma unroll
    for (int i = 0; i < 4; i++)
        #pragma unroll
        for (int j = 0; j < 4; j++) acc[i][j] = (i32x4){0, 0, 0, 0};
    i32x4 bcur[4];
    #pragma unroll
    for (int nt = 0; nt < 4; nt++) bcur[nt] = *(const i32x4*)(wb + (size_t)nt * 4096);
    for (int step = 0; step < 4; step++) {
        i32x4 af[4];
        #pragma unroll
        for (int mt = 0; mt < 4; mt++)
            af[mt] = *(const i32x4*)&AsU[(size_t)(mt * 16 + col) * ASTR + step * 16 + quad * 4];
        i32x4 bnx[4];
        if (step < 3) {
            #pragma unroll
            for (int nt = 0; nt < 4; nt++) bnx[nt] = *(const i32x4*)(wb + (size_t)nt * 4096 + (step + 1) * 64);
        }
        #pragma unroll
        for (int mt = 0; mt < 4; mt++)
            #pragma unroll
            for (int nt = 0; nt < 4; nt++)
                acc[mt][nt] = __builtin_amdgcn_mfma_i32_16x16x64_i8(af[mt], bcur[nt], acc[mt][nt], 0, 0, 0);
        if (step < 3) {
            #pragma unroll
            for (int nt = 0; nt < 4; nt++) bcur[nt] = bnx[nt];
        }
    }
    if (tid < 64) BpT[tid] = BpW[0][tid] + BpW[1][tid] + BpW[2][tid] + BpW[3][tid];
    __syncthreads();
    float alpha = sc[11] * sc[9];                       // sw*s2   (D coeff)
    float beta  = sc[11] * sc[8] + 128.f * alpha;       // W[co] coeff (offset-folded)
    float gamma = sc[10] * sc[9] + 128.f * alpha;       // Bp coeff  (offset-folded)
    float delta = 256.f * sc[10] * sc[8] - 4194304.f * alpha;
    float Wv[4];
    #pragma unroll
    for (int nt = 0; nt < 4; nt++) Wv[nt] = Wsum[w * 64 + nt * 16 + col];
    float snn[4], sxx[4], ssm[4];
    #pragma unroll
    for (int nt = 0; nt < 4; nt++) { snn[nt] = INFINITY; sxx[nt] = -INFINITY; ssm[nt] = 0.f; }
    float* obase = o2 + ((size_t)b * HW + p0) * 256 + w * 64 + col;
    #pragma unroll
    for (int mt = 0; mt < 4; mt++) {
        float bp4[4];
        #pragma unroll
        for (int r = 0; r < 4; r++) bp4[r] = BpT[mt * 16 + quad * 4 + r];
        #pragma unroll
        for (int nt = 0; nt < 4; nt++) {
            float wterm = beta * Wv[nt] + delta;
            #pragma unroll
            for (int r = 0; r < 4; r++) {
                float val = alpha * (float)acc[mt][nt][r] + gamma * bp4[r] + wterm;
                obase[(size_t)(mt * 16 + quad * 4 + r) * 256 + nt * 16] = val;
                snn[nt] = fminf(snn[nt], val);
                sxx[nt] = fmaxf(sxx[nt], val);
                ssm[nt] += val;
            }
        }
    }
    #pragma unroll
    for (int nt = 0; nt < 4; nt++) {
        snn[nt] = fminf(snn[nt], __shfl_xor(snn[nt], 16));
        sxx[nt] = fmaxf(sxx[nt], __shfl_xor(sxx[nt], 16));
        ssm[nt] += __shfl_xor(ssm[nt], 16);
        snn[nt] = fminf(snn[nt], __shfl_xor(snn[nt], 32));
        sxx[nt] = fmaxf(sxx[nt], __shfl_xor(sxx[nt], 32));
        ssm[nt] += __shfl_xor(ssm[nt], 32);
    }
    if (lane < 16) {
        #pragma unroll
        for (int nt = 0; nt < 4; nt++) {
            int idx = b * 256 + w * 64 + nt * 16 + lane;
            atomicMin(&o2mn[idx], enc(snn[nt]));
            atomicMax(&o2mx[idx], enc(sxx[nt]));
            atomicAdd(&o2sum[idx], ssm[nt]);
        }
    }
}

// out2-derived scalars/coeffs, wave-parallel phase 1, unrolled loads.
__global__ __launch_bounds__(256) void k_stats2(const unsigned* __restrict__ o2mnU, const unsigned* __restrict__ o2mxU,
                                                const float* __restrict__ o2sm,
                                                const float* __restrict__ bn2w, const float* __restrict__ bn2b,
                                                float* sc, float* __restrict__ P2, float* __restrict__ Q2) {
    int tid = threadIdx.x, lane = tid & 63, w = tid >> 6;
    __shared__ float bmn[32], bmx[32], sp[2];
    #pragma unroll
    for (int i = 0; i < 8; i++) {
        int b = w * 8 + i;
        uint4 um = *(const uint4*)&o2mnU[b * 256 + lane * 4];
        uint4 ux = *(const uint4*)&o2mxU[b * 256 + lane * 4];
        float mn = fminf(fminf(dec(um.x), dec(um.y)), fminf(dec(um.z), dec(um.w)));
        float mx = fmaxf(fmaxf(dec(ux.x), dec(ux.y)), fmaxf(dec(ux.z), dec(ux.w)));
        #pragma unroll
        for (int o = 32; o > 0; o >>= 1) { mn = fminf(mn, __shfl_down(mn, o)); mx = fmaxf(mx, __shfl_down(mx, o)); }
        if (lane == 0) { bmn[b] = mn; bmx[b] = mx; }
    }
    __syncthreads();
    if (tid == 0) {
        float sm = 0.f, sx = 0.f;
        for (int i = 0; i < 32; i++) { sm += bmn[i]; sx += bmx[i]; }
        float m = sm / 32.f, X = sx / 32.f;
        sp[0] = m; sp[1] = fmaxf((X - m) / 255.f, 1e-8f);
        sc[12] = sp[0]; sc[13] = sp[1];
    }
    __syncthreads();
    float mno = sp[0], so = sp[1];
    int c = tid;
    float mmax = 0.f, mmin = 0.f, sum = 0.f;
    #pragma unroll
    for (int ck = 0; ck < 16; ck++) {
        float c0n = dec(o2mnU[(2 * ck) * 256 + c]), c1n = dec(o2mnU[(2 * ck + 1) * 256 + c]);
        float c0x = dec(o2mxU[(2 * ck) * 256 + c]), c1x = dec(o2mxU[(2 * ck + 1) * 256 + c]);
        mmin += qz(fminf(c0n, c1n), mno, so);
        mmax += qz(fmaxf(c0x, c1x), mno, so);
        sum  += o2sm[(2 * ck) * 256 + c] + o2sm[(2 * ck + 1) * 256 + c];
    }
    mmin *= 0.0625f; mmax *= 0.0625f;
    float mean = sum / 100352.f;
    const float scale_fix = (float)(0.175 * (1.0 + sqrt(3.14159265358979323846 * log(4.0))) / sqrt(2.0 * log(6272.0)));
    float scale = 1.f / ((mmax - mmin) * scale_fix + 1e-5f);
    float ssn = scale, ssx = scale;
    blk_red_minmax_bcast(ssn, ssx);
    float wv = bn2w[c];
    float wmn = wv, wmx = wv;
    blk_red_minmax_bcast(wmn, wmx);
    float qs = qz(scale, ssn, fmaxf((ssx - ssn) / 255.f, 1e-8f));
    float qw = qz(wv, wmn, fmaxf((wmx - wmn) / 255.f, 1e-8f));
    float a2 = qs * qw;
    float be = bn2b[c] - mean * a2;
    P2[c] = so * a2; Q2[c] = mno * a2 + be;
}

// final: transpose [b][p][co] -> NCHW [b][co][p] via LDS tile, map applied on write side
__global__ __launch_bounds__(256) void k_apply(const float* __restrict__ o2, const float* __restrict__ sc,
                                               const float* __restrict__ P2, const float* __restrict__ Q2,
                                               float* __restrict__ out) {
    __shared__ float tile[64][65];
    int b = blockIdx.z, p0 = blockIdx.x * 64, co0 = blockIdx.y * 64;
    int t = threadIdx.x, rr = t >> 4, cq = t & 15;
    float mno = sc[12], so = sc[13];
    #pragma unroll
    for (int it = 0; it < 4; it++) {
        int p = rr + 16 * it;
        float4 v = *(const float4*)&o2[((size_t)b * HW + p0 + p) * 256 + co0 + cq * 4];
        *(float4*)&tile[p][cq * 4] = v;
    }
    __syncthreads();
    #pragma unroll
    for (int it = 0; it < 4; it++) {
        int col = rr + 16 * it;             // local co
        int c = co0 + col;
        float pv = P2[c], qv = Q2[c];
        float4 r;
        #pragma unroll
        for (int j = 0; j < 4; j++) {
            float val = tile[cq * 4 + j][col];
            (&r.x)[j] = fmaxf(rintf(fminf(fmaxf((val - mno) / so, 0.f), 255.f)) * pv + qv, 0.f);
        }
        *(float4*)&out[((size_t)b * 256 + c) * HW + p0 + cq * 4] = r;
    }
}

// ---------- launch ----------

extern "C" void kernel_launch(void* const* d_in, const int* in_sizes, int n_in,
                              void* d_out, int out_size, void* d_ws, size_t ws_size,
                              hipStream_t stream) {
    (void)in_sizes; (void)n_in; (void)out_size; (void)ws_size;
    const float* x    = (const float*)d_in[0];
    const float* dww  = (const float*)d_in[1];
    const float* dwb  = (const float*)d_in[2];
    const float* bn1w = (const float*)d_in[3];
    const float* bn1b = (const float*)d_in[4];
    const float* pww  = (const float*)d_in[5];
    const float* bn2w = (const float*)d_in[6];
    const float* bn2b = (const float*)d_in[7];

    float* h1   = (float*)d_ws;                  // TOT  [b][ci][p]
    float* o2   = h1 + TOT;                      // TOT  [b][p][co]
    float* after = o2 + TOT;
    char* wcodes = (char*)after;                 // 65536 bytes = 16384 floats
    float* Wsum  = after + 16384;                // 256
    float* sc    = Wsum + 256;                   // 32
    unsigned* xsl   = (unsigned*)(sc + 32);      // 64
    unsigned* pwsl  = xsl + 64;                  // 2 (padded 64)
    unsigned* o2mnU = pwsl + 64;                 // 8192
    unsigned* o2mxU = o2mnU + 8192;              // 8192
    float* o2sm = (float*)(o2mxU + 8192);        // 8192
    float* h1mn = o2sm + 8192;                   // 8192
    float* h1mx = h1mn + 8192;                   // 8192
    float* h1sm = h1mx + 8192;                   // 8192
    float* P2 = h1sm + 8192; float* Q2 = P2 + 256;
    float* A2v = Q2 + 256;   float* B2v = A2v + 256;

    k_init<<<32, 256, 0, stream>>>(xsl, pwsl, o2mnU, o2mxU, o2sm);
    k_front<<<576, 256, 0, stream>>>((const float4*)x, (const float4*)pww, xsl, pwsl);
    k_fin1<<<1, 256, 0, stream>>>(dww, dwb, xsl, pwsl, sc);
    k_qw<<<256, 256, 0, stream>>>(pww, sc, wcodes, Wsum);
    k_dwconv<<<NB * NCH, 256, 0, stream>>>((const float4*)x, dww, dwb, h1, sc, h1mn, h1mx, h1sm);
    k_stats1<<<1, 256, 0, stream>>>(h1mn, h1mx, h1sm, bn1w, bn1b, sc, A2v, B2v);
    k_gemm<<<dim3(49, 32), 256, 0, stream>>>(h1, wcodes, Wsum, sc, A2v, B2v, o2, o2mnU, o2mxU, o2sm);
    k_stats2<<<1, 256, 0, stream>>>(o2mnU, o2mxU, o2sm, bn2w, bn2b, sc, P2, Q2);
    k_apply<<<dim3(49, 4, 32), 256, 0, stream>>>(o2, sc, P2, Q2, (float*)d_out);
}